// Round 1
// baseline (8376.284 us; speedup 1.0000x reference)
//
#include <hip/hip_runtime.h>
#include <cstdint>
#include <cmath>

#define D_MODEL 1024
#define T_SEQ   1024
#define NHEAD   16
#define NLAYER  8
#define HID     2734
#define HID_PAD 2736
#define NTOK    2048
#define VOCAB   32000

typedef __bf16 bf16x8 __attribute__((ext_vector_type(8)));
typedef __bf16 bf16x4 __attribute__((ext_vector_type(4)));
typedef float  f32x4  __attribute__((ext_vector_type(4)));

__device__ inline bf16x4 to_bf4(float a, float b, float c, float d) {
  bf16x4 t; t[0] = (__bf16)a; t[1] = (__bf16)b; t[2] = (__bf16)c; t[3] = (__bf16)d; return t;
}

// ---------------------------------------------------------------------------
// Embedding gather: x[t,:] = W_emb[idx[t],:]
// ---------------------------------------------------------------------------
__global__ __launch_bounds__(256) void embed_kernel(const int* __restrict__ idx,
                                                    const float* __restrict__ W,
                                                    float* __restrict__ x) {
  int t = blockIdx.x;
  int v = idx[t];
  float4 val = *(const float4*)&W[(size_t)v * D_MODEL + threadIdx.x * 4];
  *(float4*)&x[(size_t)t * D_MODEL + threadIdx.x * 4] = val;
}

// ---------------------------------------------------------------------------
// RMSNorm: one block per row (D=1024, 256 thr x 4)
// ---------------------------------------------------------------------------
__global__ __launch_bounds__(256) void rmsnorm_kernel(const float* __restrict__ x,
                                                      const float* __restrict__ w,
                                                      float* __restrict__ out) {
  int row = blockIdx.x;
  int tid = threadIdx.x;
  float4 v = *(const float4*)&x[(size_t)row * D_MODEL + tid * 4];
  float s = v.x * v.x + v.y * v.y + v.z * v.z + v.w * v.w;
#pragma unroll
  for (int m = 32; m >= 1; m >>= 1) s += __shfl_xor(s, m, 64);
  __shared__ float red[4];
  if ((tid & 63) == 0) red[tid >> 6] = s;
  __syncthreads();
  float tot = red[0] + red[1] + red[2] + red[3];
  float inv = rsqrtf(tot * (1.0f / (float)D_MODEL) + 1e-6f);
  float4 wv = *(const float4*)&w[tid * 4];
  float4 o4;
  o4.x = v.x * inv * wv.x; o4.y = v.y * inv * wv.y;
  o4.z = v.z * inv * wv.z; o4.w = v.w * inv * wv.w;
  *(float4*)&out[(size_t)row * D_MODEL + tid * 4] = o4;
}

// ---------------------------------------------------------------------------
// RoPE in-place on q and k sections of qkv. One thread per (row, pair).
// pairs: i in [0,32). rows: b*T*H*2 sections (q,k).
// ---------------------------------------------------------------------------
__global__ __launch_bounds__(256) void rope_kernel(float* __restrict__ qkv) {
  int p = blockIdx.x * 256 + threadIdx.x;   // 0 .. 2*32768*32-1
  int i = p & 31;
  int row = p >> 5;                          // 0..65535
  int sec = row & 1;                         // 0=q, 1=k
  int r2 = row >> 1;                         // (b,t,h)
  int h = r2 & 15;
  int t = (r2 >> 4) & 1023;
  int b = r2 >> 14;
  size_t base = ((size_t)(b * T_SEQ + t)) * (3 * D_MODEL) + sec * D_MODEL + h * 64;
  // inv_freq = 10000^(-i/32) = 2^(-i/32 * log2(10000))
  float freq = exp2f(-(float)i * (13.287712379549449f / 32.0f));
  float ang = (float)t * freq;
  float sn, cs;
  sincosf(ang, &sn, &cs);
  float a = qkv[base + i];
  float bb = qkv[base + 32 + i];
  qkv[base + i]      = a * cs - bb * sn;
  qkv[base + 32 + i] = a * sn + bb * cs;
}

// ---------------------------------------------------------------------------
// SiLU gate: g = silu(g) * u   (g,u are [NTOK][HID_PAD], pad cols -> 0)
// ---------------------------------------------------------------------------
__global__ __launch_bounds__(256) void silu_kernel(float* __restrict__ g,
                                                   const float* __restrict__ u) {
  size_t i = (size_t)blockIdx.x * 256 + threadIdx.x;
  int col = (int)(i % HID_PAD);
  float gv = g[i];
  float r = 0.f;
  if (col < HID) {
    float uv = u[i];
    r = gv / (1.f + expf(-gv)) * uv;
  }
  g[i] = r;
}

// ---------------------------------------------------------------------------
// GEMM: C[M,N] = A[M,K] @ B  (+ optional residual Cin)
// BT=false: B is [K,N] row-major (ldb = row stride)
// BT=true : B is [N,K] row-major
// 128x128 tile, 4 waves (2x2), each wave 64x64 via 4x4 frags of 16x16x32 bf16.
// ---------------------------------------------------------------------------
template <int EPI, bool BT>
__global__ __launch_bounds__(256) void gemm_kernel(const float* __restrict__ A,
                                                   const float* __restrict__ B,
                                                   const float* __restrict__ Cin,
                                                   float* __restrict__ C,
                                                   int M, int N, int K,
                                                   int lda, int ldb, int ldc) {
  __shared__ __align__(16) __bf16 lsA[128][40];
  __shared__ __align__(16) __bf16 lsB[128][40];
  const int tid = threadIdx.x;
  const int lane = tid & 63;
  const int wid = tid >> 6;
  const int wr = wid >> 1, wc = wid & 1;
  const int lr = lane & 15, lg = lane >> 4;
  const int brow = blockIdx.x * 128;
  const int bcol = blockIdx.y * 128;

  f32x4 acc[4][4];
#pragma unroll
  for (int m = 0; m < 4; ++m)
#pragma unroll
    for (int n = 0; n < 4; ++n) acc[m][n] = (f32x4){0.f, 0.f, 0.f, 0.f};

  for (int k0 = 0; k0 < K; k0 += 32) {
    // ---- stage A tile: 128 rows x 32 k
#pragma unroll
    for (int i = 0; i < 4; ++i) {
      int idx = tid + i * 256;
      int row = idx >> 3, kq = idx & 7;
      int gr = brow + row, gk = k0 + kq * 4;
      float vx = 0.f, vy = 0.f, vz = 0.f, vw = 0.f;
      if (gr < M) {
        const float* ap = A + (size_t)gr * lda + gk;
        if (gk + 4 <= K) {
          float4 v = *(const float4*)ap;
          vx = v.x; vy = v.y; vz = v.z; vw = v.w;
        } else {
          if (gk + 0 < K) vx = ap[0];
          if (gk + 1 < K) vy = ap[1];
          if (gk + 2 < K) vz = ap[2];
          if (gk + 3 < K) vw = ap[3];
        }
      }
      *(bf16x4*)&lsA[row][kq * 4] = to_bf4(vx, vy, vz, vw);
    }
    // ---- stage B tile (into [n][k] layout)
    if (!BT) {
#pragma unroll
      for (int i = 0; i < 4; ++i) {
        int idx = tid + i * 256;
        int kk = idx >> 5, nq = idx & 31;
        int gk = k0 + kk, gn = bcol + nq * 4;
        float vx = 0.f, vy = 0.f, vz = 0.f, vw = 0.f;
        if (gk < K) {
          const float* bp = B + (size_t)gk * ldb + gn;
          if (gn + 4 <= N) {
            if ((ldb & 3) == 0) {
              float4 v = *(const float4*)bp;
              vx = v.x; vy = v.y; vz = v.z; vw = v.w;
            } else {
              float2 a2 = *(const float2*)bp;
              float2 b2 = *(const float2*)(bp + 2);
              vx = a2.x; vy = a2.y; vz = b2.x; vw = b2.y;
            }
          } else {
            if (gn + 0 < N) vx = bp[0];
            if (gn + 1 < N) vy = bp[1];
            if (gn + 2 < N) vz = bp[2];
            if (gn + 3 < N) vw = bp[3];
          }
        }
        lsB[nq * 4 + 0][kk] = (__bf16)vx;
        lsB[nq * 4 + 1][kk] = (__bf16)vy;
        lsB[nq * 4 + 2][kk] = (__bf16)vz;
        lsB[nq * 4 + 3][kk] = (__bf16)vw;
      }
    } else {
#pragma unroll
      for (int i = 0; i < 4; ++i) {
        int idx = tid + i * 256;
        int row = idx >> 3, kq = idx & 7;
        int gn = bcol + row, gk = k0 + kq * 4;
        float vx = 0.f, vy = 0.f, vz = 0.f, vw = 0.f;
        if (gn < N) {
          const float* bp = B + (size_t)gn * ldb + gk;
          if (gk + 4 <= K) {
            float4 v = *(const float4*)bp;
            vx = v.x; vy = v.y; vz = v.z; vw = v.w;
          } else {
            if (gk + 0 < K) vx = bp[0];
            if (gk + 1 < K) vy = bp[1];
            if (gk + 2 < K) vz = bp[2];
            if (gk + 3 < K) vw = bp[3];
          }
        }
        *(bf16x4*)&lsB[row][kq * 4] = to_bf4(vx, vy, vz, vw);
      }
    }
    __syncthreads();
    // ---- compute
    bf16x8 af[4], bfr[4];
#pragma unroll
    for (int m = 0; m < 4; ++m)
      af[m] = *(bf16x8*)&lsA[wr * 64 + m * 16 + lr][lg * 8];
#pragma unroll
    for (int n = 0; n < 4; ++n)
      bfr[n] = *(bf16x8*)&lsB[wc * 64 + n * 16 + lr][lg * 8];
#pragma unroll
    for (int m = 0; m < 4; ++m)
#pragma unroll
      for (int n = 0; n < 4; ++n)
        acc[m][n] = __builtin_amdgcn_mfma_f32_16x16x32_bf16(af[m], bfr[n], acc[m][n], 0, 0, 0);
    __syncthreads();
  }

  // ---- epilogue
#pragma unroll
  for (int m = 0; m < 4; ++m) {
#pragma unroll
    for (int n = 0; n < 4; ++n) {
#pragma unroll
      for (int r = 0; r < 4; ++r) {
        int row = brow + wr * 64 + m * 16 + lg * 4 + r;
        int col = bcol + wc * 64 + n * 16 + lr;
        if (row < M && col < N) {
          float v = acc[m][n][r];
          if (EPI == 1) v += Cin[(size_t)row * ldc + col];
          C[(size_t)row * ldc + col] = v;
        }
      }
    }
  }
}

// ---------------------------------------------------------------------------
// Flash attention: block = (q-block of 64 rows, one (b,h)). 4 waves x 16 q-rows.
// qkv layout per token row (3*D): [q(16x64) | k(16x64) | v(16x64)]
// ---------------------------------------------------------------------------
__global__ __launch_bounds__(256) void attn_kernel(const float* __restrict__ qkv,
                                                   float* __restrict__ o) {
  __shared__ __align__(16) __bf16 lsQ[64][72];
  __shared__ __align__(16) __bf16 lsK[64][72];
  __shared__ __align__(16) __bf16 lsVt[64][72];
  __shared__ __align__(16) __bf16 lsP[4][16][72];
  const int tid = threadIdx.x;
  const int lane = tid & 63;
  const int w = tid >> 6;
  const int lr = lane & 15, lg = lane >> 4;
  const int bh = blockIdx.y, b = bh >> 4, h = bh & 15;
  const int q0 = blockIdx.x * 64;
  const size_t base_bh = ((size_t)b * T_SEQ) * (3 * D_MODEL) + h * 64;
  const float scale = 0.125f;  // 1/sqrt(64)

  // stage Q (64 x 64)
#pragma unroll
  for (int i = 0; i < 4; ++i) {
    int idx = tid + i * 256, row = idx >> 4, dq = idx & 15;
    float4 v = *(const float4*)&qkv[base_bh + (size_t)(q0 + row) * (3 * D_MODEL) + dq * 4];
    *(bf16x4*)&lsQ[row][dq * 4] = to_bf4(v.x, v.y, v.z, v.w);
  }

  f32x4 accO[4];
#pragma unroll
  for (int n = 0; n < 4; ++n) accO[n] = (f32x4){0.f, 0.f, 0.f, 0.f};
  float mrow[4], lrow[4];
#pragma unroll
  for (int r = 0; r < 4; ++r) { mrow[r] = -1e30f; lrow[r] = 0.f; }
  const int qw0 = q0 + w * 16;

  for (int j0 = 0; j0 <= q0; j0 += 64) {
    __syncthreads();  // protects K/V overwrite; first iter also covers Q staging
    // stage K and V^T tiles (64 x 64)
#pragma unroll
    for (int i = 0; i < 4; ++i) {
      int idx = tid + i * 256, row = idx >> 4, dq = idx & 15;
      float4 kv = *(const float4*)&qkv[base_bh + D_MODEL + (size_t)(j0 + row) * (3 * D_MODEL) + dq * 4];
      *(bf16x4*)&lsK[row][dq * 4] = to_bf4(kv.x, kv.y, kv.z, kv.w);
      float4 vv = *(const float4*)&qkv[base_bh + 2 * D_MODEL + (size_t)(j0 + row) * (3 * D_MODEL) + dq * 4];
      lsVt[dq * 4 + 0][row] = (__bf16)vv.x;
      lsVt[dq * 4 + 1][row] = (__bf16)vv.y;
      lsVt[dq * 4 + 2][row] = (__bf16)vv.z;
      lsVt[dq * 4 + 3][row] = (__bf16)vv.w;
    }
    __syncthreads();

    // S = Q K^T  (16 q-rows x 64 j-cols per wave)
    f32x4 s4[4];
#pragma unroll
    for (int n = 0; n < 4; ++n) s4[n] = (f32x4){0.f, 0.f, 0.f, 0.f};
#pragma unroll
    for (int kk = 0; kk < 2; ++kk) {
      bf16x8 aq = *(bf16x8*)&lsQ[w * 16 + lr][kk * 32 + lg * 8];
#pragma unroll
      for (int n = 0; n < 4; ++n) {
        bf16x8 bk = *(bf16x8*)&lsK[n * 16 + lr][kk * 32 + lg * 8];
        s4[n] = __builtin_amdgcn_mfma_f32_16x16x32_bf16(aq, bk, s4[n], 0, 0, 0);
      }
    }

    // scale + causal mask + row max
    float pm[4];
#pragma unroll
    for (int r = 0; r < 4; ++r) pm[r] = -1e30f;
#pragma unroll
    for (int n = 0; n < 4; ++n) {
      int gj = j0 + n * 16 + lr;
#pragma unroll
      for (int r = 0; r < 4; ++r) {
        int gq = qw0 + lg * 4 + r;
        float sv = s4[n][r] * scale;
        if (gj > gq) sv = -1e30f;
        s4[n][r] = sv;
        pm[r] = fmaxf(pm[r], sv);
      }
    }
#pragma unroll
    for (int r = 0; r < 4; ++r) {
#pragma unroll
      for (int m = 8; m >= 1; m >>= 1) pm[r] = fmaxf(pm[r], __shfl_xor(pm[r], m, 64));
    }
    // online softmax update
    float alpha[4];
#pragma unroll
    for (int r = 0; r < 4; ++r) {
      float mn = fmaxf(mrow[r], pm[r]);
      alpha[r] = expf(mrow[r] - mn);
      mrow[r] = mn;
    }
    float ps[4] = {0.f, 0.f, 0.f, 0.f};
#pragma unroll
    for (int n = 0; n < 4; ++n) {
#pragma unroll
      for (int r = 0; r < 4; ++r) {
        float p = expf(s4[n][r] - mrow[r]);
        s4[n][r] = p;
        ps[r] += p;
      }
    }
#pragma unroll
    for (int r = 0; r < 4; ++r) {
#pragma unroll
      for (int m = 8; m >= 1; m >>= 1) ps[r] += __shfl_xor(ps[r], m, 64);
      lrow[r] = lrow[r] * alpha[r] + ps[r];
    }
#pragma unroll
    for (int n = 0; n < 4; ++n) {
#pragma unroll
      for (int r = 0; r < 4; ++r) accO[n][r] *= alpha[r];
    }
    // P -> LDS (per-wave), then PV
#pragma unroll
    for (int n = 0; n < 4; ++n) {
#pragma unroll
      for (int r = 0; r < 4; ++r) lsP[w][lg * 4 + r][n * 16 + lr] = (__bf16)s4[n][r];
    }
    asm volatile("s_waitcnt lgkmcnt(0)" ::: "memory");
    __builtin_amdgcn_sched_barrier(0);
#pragma unroll
    for (int kk = 0; kk < 2; ++kk) {
      bf16x8 ap = *(bf16x8*)&lsP[w][lr][kk * 32 + lg * 8];
#pragma unroll
      for (int n = 0; n < 4; ++n) {
        bf16x8 bv = *(bf16x8*)&lsVt[n * 16 + lr][kk * 32 + lg * 8];
        accO[n] = __builtin_amdgcn_mfma_f32_16x16x32_bf16(ap, bv, accO[n], 0, 0, 0);
      }
    }
  }

  // write O
#pragma unroll
  for (int n = 0; n < 4; ++n) {
#pragma unroll
    for (int r = 0; r < 4; ++r) {
      int gq = qw0 + lg * 4 + r;
      float val = accO[n][r] / lrow[r];
      o[(size_t)(b * T_SEQ + gq) * D_MODEL + h * 64 + n * 16 + lr] = val;
    }
  }
}

// ---------------------------------------------------------------------------
extern "C" void kernel_launch(void* const* d_in, const int* in_sizes, int n_in,
                              void* d_out, int out_size, void* d_ws, size_t ws_size,
                              hipStream_t stream) {
  const int*   idx     = (const int*)d_in[0];
  const float* W_emb   = (const float*)d_in[1];
  const float* norm1_w = (const float*)d_in[2];
  const float* Wqkv    = (const float*)d_in[3];
  const float* Wout    = (const float*)d_in[4];
  const float* norm2_w = (const float*)d_in[5];
  const float* Wg      = (const float*)d_in[6];
  const float* Wu      = (const float*)d_in[7];
  const float* Wd      = (const float*)d_in[8];
  const float* fnorm   = (const float*)d_in[9];
  float* out = (float*)d_out;

  float* x   = (float*)d_ws;
  float* h   = x + (size_t)NTOK * D_MODEL;
  float* qkv = h + (size_t)NTOK * D_MODEL;
  float* o   = qkv + (size_t)NTOK * 3 * D_MODEL;
  float* g   = o + (size_t)NTOK * D_MODEL;
  float* u   = g + (size_t)NTOK * HID_PAD;

  embed_kernel<<<NTOK, 256, 0, stream>>>(idx, W_emb, x);
  for (int l = 0; l < NLAYER; ++l) {
    rmsnorm_kernel<<<NTOK, 256, 0, stream>>>(x, norm1_w + (size_t)l * D_MODEL, h);
    gemm_kernel<0, false><<<dim3(16, 24), 256, 0, stream>>>(
        h, Wqkv + (size_t)l * D_MODEL * 3 * D_MODEL, nullptr, qkv,
        NTOK, 3 * D_MODEL, D_MODEL, D_MODEL, 3 * D_MODEL, 3 * D_MODEL);
    rope_kernel<<<8192, 256, 0, stream>>>(qkv);
    attn_kernel<<<dim3(16, 32), 256, 0, stream>>>(qkv, o);
    gemm_kernel<1, false><<<dim3(16, 8), 256, 0, stream>>>(
        o, Wout + (size_t)l * D_MODEL * D_MODEL, x, x,
        NTOK, D_MODEL, D_MODEL, D_MODEL, D_MODEL, D_MODEL);
    rmsnorm_kernel<<<NTOK, 256, 0, stream>>>(x, norm2_w + (size_t)l * D_MODEL, h);
    gemm_kernel<0, false><<<dim3(16, 22), 256, 0, stream>>>(
        h, Wg + (size_t)l * D_MODEL * HID, nullptr, g,
        NTOK, HID, D_MODEL, D_MODEL, HID, HID_PAD);
    gemm_kernel<0, false><<<dim3(16, 22), 256, 0, stream>>>(
        h, Wu + (size_t)l * D_MODEL * HID, nullptr, u,
        NTOK, HID, D_MODEL, D_MODEL, HID, HID_PAD);
    silu_kernel<<<(NTOK * HID_PAD) / 256, 256, 0, stream>>>(g, u);
    gemm_kernel<1, false><<<dim3(16, 8), 256, 0, stream>>>(
        g, Wd + (size_t)l * HID * D_MODEL, x, x,
        NTOK, D_MODEL, HID, HID_PAD, D_MODEL, D_MODEL);
  }
  rmsnorm_kernel<<<NTOK, 256, 0, stream>>>(x, fnorm, h);
  gemm_kernel<0, true><<<dim3(16, 250), 256, 0, stream>>>(
      h, W_emb, nullptr, out,
      NTOK, VOCAB, D_MODEL, D_MODEL, D_MODEL, VOCAB);
}

// Round 2
// 2515.096 us; speedup vs baseline: 3.3304x; 3.3304x over previous
//
#include <hip/hip_runtime.h>
#include <cstdint>
#include <cmath>

#define D_MODEL 1024
#define T_SEQ   1024
#define NHEAD   16
#define NLAYER  8
#define HID     2734
#define HID_PAD 2816
#define NTOK    2048
#define VOCAB   32000

typedef __bf16 bf16x8 __attribute__((ext_vector_type(8)));
typedef __bf16 bf16x4 __attribute__((ext_vector_type(4)));
typedef float  f32x4  __attribute__((ext_vector_type(4)));

__device__ inline bf16x4 to_bf4(float a, float b, float c, float d) {
  bf16x4 t; t[0] = (__bf16)a; t[1] = (__bf16)b; t[2] = (__bf16)c; t[3] = (__bf16)d; return t;
}

__device__ inline void gload16(const __bf16* g, __bf16* l) {
  __builtin_amdgcn_global_load_lds(
      (const __attribute__((address_space(1))) void*)g,
      (__attribute__((address_space(3))) void*)l, 16, 0, 0);
}

// ---------------------------------------------------------------------------
// Embedding gather: x[t,:] = W_emb[idx[t],:]  (f32)
// ---------------------------------------------------------------------------
__global__ __launch_bounds__(256) void embed_kernel(const int* __restrict__ idx,
                                                    const float* __restrict__ W,
                                                    float* __restrict__ x) {
  int t = blockIdx.x;
  int v = idx[t];
  float4 val = *(const float4*)&W[(size_t)v * D_MODEL + threadIdx.x * 4];
  *(float4*)&x[(size_t)t * D_MODEL + threadIdx.x * 4] = val;
}

// ---------------------------------------------------------------------------
// RMSNorm: f32 in -> bf16 out. One block per row.
// ---------------------------------------------------------------------------
__global__ __launch_bounds__(256) void rmsnorm_kernel(const float* __restrict__ x,
                                                      const float* __restrict__ w,
                                                      __bf16* __restrict__ out) {
  int row = blockIdx.x;
  int tid = threadIdx.x;
  float4 v = *(const float4*)&x[(size_t)row * D_MODEL + tid * 4];
  float s = v.x * v.x + v.y * v.y + v.z * v.z + v.w * v.w;
#pragma unroll
  for (int m = 32; m >= 1; m >>= 1) s += __shfl_xor(s, m, 64);
  __shared__ float red[4];
  if ((tid & 63) == 0) red[tid >> 6] = s;
  __syncthreads();
  float tot = red[0] + red[1] + red[2] + red[3];
  float inv = rsqrtf(tot * (1.0f / (float)D_MODEL) + 1e-6f);
  float4 wv = *(const float4*)&w[tid * 4];
  bf16x4 o4 = to_bf4(v.x * inv * wv.x, v.y * inv * wv.y, v.z * inv * wv.z, v.w * inv * wv.w);
  *(bf16x4*)&out[(size_t)row * D_MODEL + tid * 4] = o4;
}

// ---------------------------------------------------------------------------
// RoPE in-place on q and k sections of qkv (f32).
// ---------------------------------------------------------------------------
__global__ __launch_bounds__(256) void rope_kernel(float* __restrict__ qkv) {
  int p = blockIdx.x * 256 + threadIdx.x;
  int i = p & 31;
  int row = p >> 5;
  int sec = row & 1;
  int r2 = row >> 1;
  int h = r2 & 15;
  int t = (r2 >> 4) & 1023;
  int b = r2 >> 14;
  size_t base = ((size_t)(b * T_SEQ + t)) * (3 * D_MODEL) + sec * D_MODEL + h * 64;
  float freq = exp2f(-(float)i * (13.287712379549449f / 32.0f));
  float ang = (float)t * freq;
  float sn, cs;
  sincosf(ang, &sn, &cs);
  float a = qkv[base + i];
  float bb = qkv[base + 32 + i];
  qkv[base + i]      = a * cs - bb * sn;
  qkv[base + 32 + i] = a * sn + bb * cs;
}

// ---------------------------------------------------------------------------
// Transpose + convert: in f32 [R][C] -> out bf16 [Co][Ro], out[c][r]=in[r][c],
// zero-filled outside. grid = (Ro/64, Co/64).
// ---------------------------------------------------------------------------
__global__ __launch_bounds__(256) void transpose_bf16_kernel(
    const float* __restrict__ in, __bf16* __restrict__ out,
    int R, int C, int Ro) {
  __shared__ __bf16 tile[64][65];
  int r0 = blockIdx.x * 64, c0 = blockIdx.y * 64;
  int tid = threadIdx.x;
  bool fullc = (c0 + 64 <= C);
#pragma unroll
  for (int i = 0; i < 4; ++i) {
    int ri = i * 16 + (tid >> 4);
    int ci = (tid & 15) * 4;
    int r = r0 + ri;
    float4 v = {0.f, 0.f, 0.f, 0.f};
    if (r < R) {
      const float* p = in + (size_t)r * C + c0 + ci;
      if (fullc) {
        v = *(const float4*)p;
      } else {
        int c = c0 + ci;
        if (c + 0 < C) v.x = p[0];
        if (c + 1 < C) v.y = p[1];
        if (c + 2 < C) v.z = p[2];
        if (c + 3 < C) v.w = p[3];
      }
    }
    tile[ri][ci + 0] = (__bf16)v.x;
    tile[ri][ci + 1] = (__bf16)v.y;
    tile[ri][ci + 2] = (__bf16)v.z;
    tile[ri][ci + 3] = (__bf16)v.w;
  }
  __syncthreads();
#pragma unroll
  for (int i = 0; i < 4; ++i) {
    int oc = i * 16 + (tid >> 4);
    int orr = (tid & 15) * 4;
    bf16x4 t;
    t[0] = tile[orr + 0][oc];
    t[1] = tile[orr + 1][oc];
    t[2] = tile[orr + 2][oc];
    t[3] = tile[orr + 3][oc];
    *(bf16x4*)&out[(size_t)(c0 + oc) * Ro + r0 + orr] = t;
  }
}

// ---------------------------------------------------------------------------
// Plain f32 -> bf16 convert (W_emb is already [N][K]).
// ---------------------------------------------------------------------------
__global__ __launch_bounds__(256) void convert_bf16_kernel(const float* __restrict__ in,
                                                           __bf16* __restrict__ out, int n4) {
  for (int i = blockIdx.x * 256 + threadIdx.x; i < n4; i += gridDim.x * 256) {
    float4 v = ((const float4*)in)[i];
    ((bf16x4*)out)[i] = to_bf4(v.x, v.y, v.z, v.w);
  }
}

// ---------------------------------------------------------------------------
// GEMM: C[M,N] = A[M,K] @ B^T  where A bf16 [M][K], B bf16 [N][K] (both row-major,
// stride K). m97 structure: 128x128 tile, BK=32, global_load_lds w=16, 4 waves.
// EPI: 0 = f32 store; 1 = f32 store + residual Cin; 2 = bf16 store silu(Cin)*acc.
// Grid covers M,N exactly (no bounds checks). XCD-bijective swizzle (m204).
// ---------------------------------------------------------------------------
template <int EPI>
__global__ __launch_bounds__(256) void gemm_bt(
    const __bf16* __restrict__ A, const __bf16* __restrict__ B,
    const float* __restrict__ Cin, void* __restrict__ Cout,
    int K, int ldc) {
  __shared__ __align__(16) __bf16 lsA[128 * 32];
  __shared__ __align__(16) __bf16 lsB[128 * 32];
  const int tid = threadIdx.x;
  const int lane = tid & 63, wid = tid >> 6;
  const int wr = wid >> 1, wc = wid & 1;
  const int lr = lane & 15, lg = lane >> 4;

  const int gx = gridDim.x;
  const int nwg = gx * gridDim.y;
  const int orig = blockIdx.y * gx + blockIdx.x;
  const int q = nwg >> 3, r8 = nwg & 7;
  const int xcd = orig & 7, loc = orig >> 3;
  const int swz = ((xcd < r8) ? xcd * (q + 1) : r8 * (q + 1) + (xcd - r8) * q) + loc;
  const int brow = (swz % gx) * 128;
  const int bcol = (swz / gx) * 128;

  const int rowA = wid * 16 + (lane >> 2);   // 0..63, j=1 adds 64
  const int kq = (lane & 3) * 8;
  const __bf16* pA = A + (size_t)(brow + rowA) * K + kq;
  const __bf16* pB = B + (size_t)(bcol + rowA) * K + kq;
  __bf16* lA = lsA + wid * 512;              // wave-uniform LDS base
  __bf16* lB = lsB + wid * 512;

  f32x4 acc[4][4];
#pragma unroll
  for (int m = 0; m < 4; ++m)
#pragma unroll
    for (int n = 0; n < 4; ++n) acc[m][n] = (f32x4){0.f, 0.f, 0.f, 0.f};

  for (int k0 = 0; k0 < K; k0 += 32) {
    gload16(pA, lA);
    gload16(pA + (size_t)64 * K, lA + 2048);
    gload16(pB, lB);
    gload16(pB + (size_t)64 * K, lB + 2048);
    pA += 32;
    pB += 32;
    __syncthreads();
    bf16x8 af[4], bfr[4];
#pragma unroll
    for (int m = 0; m < 4; ++m)
      af[m] = *(bf16x8*)&lsA[(wr * 64 + m * 16 + lr) * 32 + lg * 8];
#pragma unroll
    for (int n = 0; n < 4; ++n)
      bfr[n] = *(bf16x8*)&lsB[(wc * 64 + n * 16 + lr) * 32 + lg * 8];
#pragma unroll
    for (int m = 0; m < 4; ++m)
#pragma unroll
      for (int n = 0; n < 4; ++n)
        acc[m][n] = __builtin_amdgcn_mfma_f32_16x16x32_bf16(af[m], bfr[n], acc[m][n], 0, 0, 0);
    __syncthreads();
  }

#pragma unroll
  for (int m = 0; m < 4; ++m) {
#pragma unroll
    for (int n = 0; n < 4; ++n) {
#pragma unroll
      for (int rr = 0; rr < 4; ++rr) {
        int row = brow + wr * 64 + m * 16 + lg * 4 + rr;
        int col = bcol + wc * 64 + n * 16 + lr;
        size_t off = (size_t)row * ldc + col;
        float v = acc[m][n][rr];
        if (EPI == 0) {
          ((float*)Cout)[off] = v;
        } else if (EPI == 1) {
          ((float*)Cout)[off] = Cin[off] + v;
        } else {
          float gv = Cin[off];
          ((__bf16*)Cout)[off] = (__bf16)(gv / (1.f + __expf(-gv)) * v);
        }
      }
    }
  }
}

// ---------------------------------------------------------------------------
// Flash attention: qkv f32 in, o bf16 out. Block = 64 q-rows x one (b,h).
// ---------------------------------------------------------------------------
__global__ __launch_bounds__(256) void attn_kernel(const float* __restrict__ qkv,
                                                   __bf16* __restrict__ o) {
  __shared__ __align__(16) __bf16 lsQ[64][72];
  __shared__ __align__(16) __bf16 lsK[64][72];
  __shared__ __align__(16) __bf16 lsVt[64][72];
  __shared__ __align__(16) __bf16 lsP[4][16][72];
  const int tid = threadIdx.x;
  const int lane = tid & 63;
  const int w = tid >> 6;
  const int lr = lane & 15, lg = lane >> 4;
  const int bh = blockIdx.y, b = bh >> 4, h = bh & 15;
  const int q0 = blockIdx.x * 64;
  const size_t base_bh = ((size_t)b * T_SEQ) * (3 * D_MODEL) + h * 64;
  const float scale = 0.125f;

#pragma unroll
  for (int i = 0; i < 4; ++i) {
    int idx = tid + i * 256, row = idx >> 4, dq = idx & 15;
    float4 v = *(const float4*)&qkv[base_bh + (size_t)(q0 + row) * (3 * D_MODEL) + dq * 4];
    *(bf16x4*)&lsQ[row][dq * 4] = to_bf4(v.x, v.y, v.z, v.w);
  }

  f32x4 accO[4];
#pragma unroll
  for (int n = 0; n < 4; ++n) accO[n] = (f32x4){0.f, 0.f, 0.f, 0.f};
  float mrow[4], lrow[4];
#pragma unroll
  for (int r = 0; r < 4; ++r) { mrow[r] = -1e30f; lrow[r] = 0.f; }
  const int qw0 = q0 + w * 16;

  for (int j0 = 0; j0 <= q0; j0 += 64) {
    __syncthreads();
#pragma unroll
    for (int i = 0; i < 4; ++i) {
      int idx = tid + i * 256, row = idx >> 4, dq = idx & 15;
      float4 kv = *(const float4*)&qkv[base_bh + D_MODEL + (size_t)(j0 + row) * (3 * D_MODEL) + dq * 4];
      *(bf16x4*)&lsK[row][dq * 4] = to_bf4(kv.x, kv.y, kv.z, kv.w);
      float4 vv = *(const float4*)&qkv[base_bh + 2 * D_MODEL + (size_t)(j0 + row) * (3 * D_MODEL) + dq * 4];
      lsVt[dq * 4 + 0][row] = (__bf16)vv.x;
      lsVt[dq * 4 + 1][row] = (__bf16)vv.y;
      lsVt[dq * 4 + 2][row] = (__bf16)vv.z;
      lsVt[dq * 4 + 3][row] = (__bf16)vv.w;
    }
    __syncthreads();

    f32x4 s4[4];
#pragma unroll
    for (int n = 0; n < 4; ++n) s4[n] = (f32x4){0.f, 0.f, 0.f, 0.f};
#pragma unroll
    for (int kk = 0; kk < 2; ++kk) {
      bf16x8 aq = *(bf16x8*)&lsQ[w * 16 + lr][kk * 32 + lg * 8];
#pragma unroll
      for (int n = 0; n < 4; ++n) {
        bf16x8 bk = *(bf16x8*)&lsK[n * 16 + lr][kk * 32 + lg * 8];
        s4[n] = __builtin_amdgcn_mfma_f32_16x16x32_bf16(aq, bk, s4[n], 0, 0, 0);
      }
    }

    float pm[4];
#pragma unroll
    for (int r = 0; r < 4; ++r) pm[r] = -1e30f;
#pragma unroll
    for (int n = 0; n < 4; ++n) {
      int gj = j0 + n * 16 + lr;
#pragma unroll
      for (int r = 0; r < 4; ++r) {
        int gq = qw0 + lg * 4 + r;
        float sv = s4[n][r] * scale;
        if (gj > gq) sv = -1e30f;
        s4[n][r] = sv;
        pm[r] = fmaxf(pm[r], sv);
      }
    }
#pragma unroll
    for (int r = 0; r < 4; ++r) {
#pragma unroll
      for (int m = 8; m >= 1; m >>= 1) pm[r] = fmaxf(pm[r], __shfl_xor(pm[r], m, 64));
    }
    float alpha[4];
#pragma unroll
    for (int r = 0; r < 4; ++r) {
      float mn = fmaxf(mrow[r], pm[r]);
      alpha[r] = expf(mrow[r] - mn);
      mrow[r] = mn;
    }
    float ps[4] = {0.f, 0.f, 0.f, 0.f};
#pragma unroll
    for (int n = 0; n < 4; ++n) {
#pragma unroll
      for (int r = 0; r < 4; ++r) {
        float p = expf(s4[n][r] - mrow[r]);
        s4[n][r] = p;
        ps[r] += p;
      }
    }
#pragma unroll
    for (int r = 0; r < 4; ++r) {
#pragma unroll
      for (int m = 8; m >= 1; m >>= 1) ps[r] += __shfl_xor(ps[r], m, 64);
      lrow[r] = lrow[r] * alpha[r] + ps[r];
    }
#pragma unroll
    for (int n = 0; n < 4; ++n) {
#pragma unroll
      for (int r = 0; r < 4; ++r) accO[n][r] *= alpha[r];
    }
#pragma unroll
    for (int n = 0; n < 4; ++n) {
#pragma unroll
      for (int r = 0; r < 4; ++r) lsP[w][lg * 4 + r][n * 16 + lr] = (__bf16)s4[n][r];
    }
    asm volatile("s_waitcnt lgkmcnt(0)" ::: "memory");
    __builtin_amdgcn_sched_barrier(0);
#pragma unroll
    for (int kk = 0; kk < 2; ++kk) {
      bf16x8 ap = *(bf16x8*)&lsP[w][lr][kk * 32 + lg * 8];
#pragma unroll
      for (int n = 0; n < 4; ++n) {
        bf16x8 bv = *(bf16x8*)&lsVt[n * 16 + lr][kk * 32 + lg * 8];
        accO[n] = __builtin_amdgcn_mfma_f32_16x16x32_bf16(ap, bv, accO[n], 0, 0, 0);
      }
    }
  }

#pragma unroll
  for (int n = 0; n < 4; ++n) {
#pragma unroll
    for (int r = 0; r < 4; ++r) {
      int gq = qw0 + lg * 4 + r;
      float val = accO[n][r] / lrow[r];
      o[(size_t)(b * T_SEQ + gq) * D_MODEL + h * 64 + n * 16 + lr] = (__bf16)val;
    }
  }
}

// ---------------------------------------------------------------------------
extern "C" void kernel_launch(void* const* d_in, const int* in_sizes, int n_in,
                              void* d_out, int out_size, void* d_ws, size_t ws_size,
                              hipStream_t stream) {
  const int*   idx     = (const int*)d_in[0];
  const float* W_emb   = (const float*)d_in[1];
  const float* norm1_w = (const float*)d_in[2];
  const float* Wqkv    = (const float*)d_in[3];
  const float* Wout    = (const float*)d_in[4];
  const float* norm2_w = (const float*)d_in[5];
  const float* Wg      = (const float*)d_in[6];
  const float* Wu      = (const float*)d_in[7];
  const float* Wd      = (const float*)d_in[8];
  const float* fnorm   = (const float*)d_in[9];
  float* out = (float*)d_out;

  // workspace layout
  float* x    = (float*)d_ws;                               // 2048*1024 f32
  float* qkv  = x + (size_t)NTOK * D_MODEL;                 // 2048*3072 f32
  float* g    = qkv + (size_t)NTOK * 3 * D_MODEL;           // 2048*2816 f32
  __bf16* hb  = (__bf16*)(g + (size_t)NTOK * HID_PAD);      // 2048*1024 bf16
  __bf16* ob  = hb + (size_t)NTOK * D_MODEL;                // 2048*1024 bf16
  __bf16* ga  = ob + (size_t)NTOK * D_MODEL;                // 2048*2816 bf16
  __bf16* wbuf = ga + (size_t)NTOK * HID_PAD;               // up to 32.77M bf16

  __bf16* wqkvT = wbuf;                                     // [3072][1024]
  __bf16* woutT = wqkvT + (size_t)3 * D_MODEL * D_MODEL;    // [1024][1024]
  __bf16* wgT   = woutT + (size_t)D_MODEL * D_MODEL;        // [2816][1024]
  __bf16* wuT   = wgT + (size_t)HID_PAD * D_MODEL;          // [2816][1024]
  __bf16* wdT   = wuT + (size_t)HID_PAD * D_MODEL;          // [1024][2816]

  embed_kernel<<<NTOK, 256, 0, stream>>>(idx, W_emb, x);

  for (int l = 0; l < NLAYER; ++l) {
    // weight conversion for this layer
    transpose_bf16_kernel<<<dim3(16, 48), 256, 0, stream>>>(
        Wqkv + (size_t)l * D_MODEL * 3 * D_MODEL, wqkvT, D_MODEL, 3 * D_MODEL, D_MODEL);
    transpose_bf16_kernel<<<dim3(16, 16), 256, 0, stream>>>(
        Wout + (size_t)l * D_MODEL * D_MODEL, woutT, D_MODEL, D_MODEL, D_MODEL);
    transpose_bf16_kernel<<<dim3(16, 44), 256, 0, stream>>>(
        Wg + (size_t)l * D_MODEL * HID, wgT, D_MODEL, HID, D_MODEL);
    transpose_bf16_kernel<<<dim3(16, 44), 256, 0, stream>>>(
        Wu + (size_t)l * D_MODEL * HID, wuT, D_MODEL, HID, D_MODEL);
    transpose_bf16_kernel<<<dim3(44, 16), 256, 0, stream>>>(
        Wd + (size_t)l * HID * D_MODEL, wdT, HID, D_MODEL, HID_PAD);

    rmsnorm_kernel<<<NTOK, 256, 0, stream>>>(x, norm1_w + (size_t)l * D_MODEL, hb);
    gemm_bt<0><<<dim3(16, 24), 256, 0, stream>>>(hb, wqkvT, nullptr, qkv, D_MODEL, 3 * D_MODEL);
    rope_kernel<<<8192, 256, 0, stream>>>(qkv);
    attn_kernel<<<dim3(16, 32), 256, 0, stream>>>(qkv, ob);
    gemm_bt<1><<<dim3(16, 8), 256, 0, stream>>>(ob, woutT, x, x, D_MODEL, D_MODEL);
    rmsnorm_kernel<<<NTOK, 256, 0, stream>>>(x, norm2_w + (size_t)l * D_MODEL, hb);
    gemm_bt<0><<<dim3(16, 22), 256, 0, stream>>>(hb, wgT, nullptr, g, D_MODEL, HID_PAD);
    gemm_bt<2><<<dim3(16, 22), 256, 0, stream>>>(hb, wuT, g, ga, D_MODEL, HID_PAD);
    gemm_bt<1><<<dim3(16, 8), 256, 0, stream>>>(ga, wdT, x, x, HID_PAD, D_MODEL);
  }

  rmsnorm_kernel<<<NTOK, 256, 0, stream>>>(x, fnorm, hb);
  convert_bf16_kernel<<<2048, 256, 0, stream>>>(W_emb, wbuf, VOCAB * D_MODEL / 4);
  gemm_bt<0><<<dim3(16, 250), 256, 0, stream>>>(hb, wbuf, nullptr, out, D_MODEL, VOCAB);
}

// Round 3
// 2469.380 us; speedup vs baseline: 3.3921x; 1.0185x over previous
//
#include <hip/hip_runtime.h>
#include <cstdint>
#include <cmath>

#define D_MODEL 1024
#define T_SEQ   1024
#define NHEAD   16
#define NLAYER  8
#define HID     2734
#define HID_PAD 2816
#define NTOK    2048
#define VOCAB   32000

typedef __bf16 bf16x8 __attribute__((ext_vector_type(8)));
typedef __bf16 bf16x4 __attribute__((ext_vector_type(4)));
typedef float  f32x4  __attribute__((ext_vector_type(4)));

__device__ inline bf16x4 to_bf4(float a, float b, float c, float d) {
  bf16x4 t; t[0] = (__bf16)a; t[1] = (__bf16)b; t[2] = (__bf16)c; t[3] = (__bf16)d; return t;
}

__device__ inline void gload16(const __bf16* g, __bf16* l) {
  __builtin_amdgcn_global_load_lds(
      (const __attribute__((address_space(1))) void*)g,
      (__attribute__((address_space(3))) void*)l, 16, 0, 0);
}

// ---------------------------------------------------------------------------
// Embedding gather
// ---------------------------------------------------------------------------
__global__ __launch_bounds__(256) void embed_kernel(const int* __restrict__ idx,
                                                    const float* __restrict__ W,
                                                    float* __restrict__ x) {
  int t = blockIdx.x;
  int v = idx[t];
  float4 val = *(const float4*)&W[(size_t)v * D_MODEL + threadIdx.x * 4];
  *(float4*)&x[(size_t)t * D_MODEL + threadIdx.x * 4] = val;
}

// ---------------------------------------------------------------------------
// RMSNorm: f32 in -> bf16 out
// ---------------------------------------------------------------------------
__global__ __launch_bounds__(256) void rmsnorm_kernel(const float* __restrict__ x,
                                                      const float* __restrict__ w,
                                                      __bf16* __restrict__ out) {
  int row = blockIdx.x;
  int tid = threadIdx.x;
  float4 v = *(const float4*)&x[(size_t)row * D_MODEL + tid * 4];
  float s = v.x * v.x + v.y * v.y + v.z * v.z + v.w * v.w;
#pragma unroll
  for (int m = 32; m >= 1; m >>= 1) s += __shfl_xor(s, m, 64);
  __shared__ float red[4];
  if ((tid & 63) == 0) red[tid >> 6] = s;
  __syncthreads();
  float tot = red[0] + red[1] + red[2] + red[3];
  float inv = rsqrtf(tot * (1.0f / (float)D_MODEL) + 1e-6f);
  float4 wv = *(const float4*)&w[tid * 4];
  bf16x4 o4 = to_bf4(v.x * inv * wv.x, v.y * inv * wv.y, v.z * inv * wv.z, v.w * inv * wv.w);
  *(bf16x4*)&out[(size_t)row * D_MODEL + tid * 4] = o4;
}

// ---------------------------------------------------------------------------
// RoPE cos/sin table: tab[0..32767]=cos[t][i], tab[32768..]=sin[t][i]
// ---------------------------------------------------------------------------
__global__ __launch_bounds__(256) void rope_table_kernel(float* __restrict__ tab) {
  int p = blockIdx.x * 256 + threadIdx.x;   // t*32+i, 32768 total
  int t = p >> 5, i = p & 31;
  float freq = exp2f(-(float)i * (13.287712379549449f / 32.0f));
  float sn, cs;
  sincosf((float)t * freq, &sn, &cs);
  tab[p] = cs;
  tab[32768 + p] = sn;
}

// ---------------------------------------------------------------------------
// Transpose + convert: in f32 [R][C] -> out bf16 [Co][Ro], zero-filled pad.
// ---------------------------------------------------------------------------
__global__ __launch_bounds__(256) void transpose_bf16_kernel(
    const float* __restrict__ in, __bf16* __restrict__ out,
    int R, int C, int Ro) {
  __shared__ __bf16 tile[64][65];
  int r0 = blockIdx.x * 64, c0 = blockIdx.y * 64;
  int tid = threadIdx.x;
  bool fullc = (c0 + 64 <= C);
#pragma unroll
  for (int i = 0; i < 4; ++i) {
    int ri = i * 16 + (tid >> 4);
    int ci = (tid & 15) * 4;
    int r = r0 + ri;
    float4 v = {0.f, 0.f, 0.f, 0.f};
    if (r < R) {
      const float* p = in + (size_t)r * C + c0 + ci;
      if (fullc) {
        v = *(const float4*)p;
      } else {
        int c = c0 + ci;
        if (c + 0 < C) v.x = p[0];
        if (c + 1 < C) v.y = p[1];
        if (c + 2 < C) v.z = p[2];
        if (c + 3 < C) v.w = p[3];
      }
    }
    tile[ri][ci + 0] = (__bf16)v.x;
    tile[ri][ci + 1] = (__bf16)v.y;
    tile[ri][ci + 2] = (__bf16)v.z;
    tile[ri][ci + 3] = (__bf16)v.w;
  }
  __syncthreads();
#pragma unroll
  for (int i = 0; i < 4; ++i) {
    int oc = i * 16 + (tid >> 4);
    int orr = (tid & 15) * 4;
    bf16x4 t;
    t[0] = tile[orr + 0][oc];
    t[1] = tile[orr + 1][oc];
    t[2] = tile[orr + 2][oc];
    t[3] = tile[orr + 3][oc];
    *(bf16x4*)&out[(size_t)(c0 + oc) * Ro + r0 + orr] = t;
  }
}

// ---------------------------------------------------------------------------
// Plain f32 -> bf16 convert
// ---------------------------------------------------------------------------
__global__ __launch_bounds__(256) void convert_bf16_kernel(const float* __restrict__ in,
                                                           __bf16* __restrict__ out, int n4) {
  for (int i = blockIdx.x * 256 + threadIdx.x; i < n4; i += gridDim.x * 256) {
    float4 v = ((const float4*)in)[i];
    ((bf16x4*)out)[i] = to_bf4(v.x, v.y, v.z, v.w);
  }
}

// ---------------------------------------------------------------------------
// 8-phase deep-pipelined GEMM: C[M,N] = A[M,K] @ B^T, A bf16 [M][K], B bf16 [N][K].
// BK=64 split in two K-half slots; counted vmcnt(8); sigma-permuted chunk layout
// (conflict-free reads with linear global_load_lds dest); setprio around MFMA.
// EPI: 0 f32, 1 f32+residual, 2 bf16 silu(Cin)*acc, 3 bf16 plain.
// Requires M%BM==0, N%BN==0, K%64==0.
// ---------------------------------------------------------------------------
template <int BM, int BN, int WM, int WN, int EPI>
__global__ __launch_bounds__(WM * WN * 64, 2) void gemm8(
    const __bf16* __restrict__ A, const __bf16* __restrict__ B,
    const float* __restrict__ Cin, void* __restrict__ Cout,
    int K, int ldc) {
  constexpr int NTH = WM * WN * 64;
  constexpr int MF = BM / (16 * WM);   // m-frags per wave
  constexpr int MG = (MF + 3) / 4;     // m-groups of 4
  static_assert(BN / WN == 64, "NF must be 4");
  __shared__ __align__(16) __bf16 lds[(BM + BN) * 128];

  const int tid = threadIdx.x;
  const int lane = tid & 63, wid = tid >> 6;
  const int wr = wid / WN, wn = wid % WN;
  const int lr = lane & 15, lg = lane >> 4;

  // XCD-bijective swizzle (m204)
  const int gx = gridDim.x;
  const int nwg = gx * gridDim.y;
  const int orig = blockIdx.y * gx + blockIdx.x;
  const int q = nwg >> 3, r8 = nwg & 7;
  const int xcd = orig & 7, loc = orig >> 3;
  const int swz = ((xcd < r8) ? xcd * (q + 1) : r8 * (q + 1) + (xcd - r8) * q) + loc;
  const int brow = (swz % gx) * BM;
  const int bcol = (swz / gx) * BN;

  // staging: chunk position p -> global (row, k-slot) via sigma^-1
  const int p0 = tid, p1 = tid + NTH;
  const int rA0 = ((p0 >> 6) << 4) | (p0 & 15), jA0 = ((p0 >> 4) & 3) * 8;
  const int rA1 = ((p1 >> 6) << 4) | (p1 & 15), jA1 = ((p1 >> 4) & 3) * 8;
  const __bf16* pA0 = A + (size_t)(brow + rA0) * K + jA0;
  const __bf16* pA1 = A + (size_t)(brow + rA1) * K + jA1;
  const __bf16* pB0 = B + (size_t)(bcol + rA0) * K + jA0;
  const __bf16* pB1 = B + (size_t)(bcol + rA1) * K + jA1;

  const int ntiles = K >> 6;

  auto STAGE = [&](int v, int kkq) {
    int vs = v < ntiles ? v : ntiles - 1;
    int ko = vs * 64 + kkq * 32;
    int sa = (v & 1) * (BM * 64) + kkq * (BM * 32);
    int sb = BM * 128 + (v & 1) * (BN * 64) + kkq * (BN * 32);
    gload16(pA0 + ko, lds + sa + p0 * 8);
    gload16(pA1 + ko, lds + sa + p1 * 8);
    gload16(pB0 + ko, lds + sb + p0 * 8);
    gload16(pB1 + ko, lds + sb + p1 * 8);
  };

  f32x4 acc[MF][4];
#pragma unroll
  for (int m = 0; m < MF; ++m)
#pragma unroll
    for (int n = 0; n < 4; ++n) acc[m][n] = (f32x4){0.f, 0.f, 0.f, 0.f};

  // prologue: 3 stage events (12 loads in flight)
  STAGE(0, 0);
  STAGE(0, 1);
  STAGE(1, 0);

  const int fragoff = lg * 128 + lr * 8;   // within K-half slot, elements

  for (int u = 0; u < ntiles; ++u) {
    const int buf = u & 1;
#pragma unroll
    for (int kk = 0; kk < 2; ++kk) {
      asm volatile("s_waitcnt vmcnt(8)" ::: "memory");
      __builtin_amdgcn_sched_barrier(0);
      __builtin_amdgcn_s_barrier();
      __builtin_amdgcn_sched_barrier(0);
      if (kk == 0) STAGE(u + 1, 1);
      else         STAGE(u + 2, 0);
      const __bf16* Ab = lds + buf * (BM * 64) + kk * (BM * 32);
      const __bf16* Bb = lds + BM * 128 + buf * (BN * 64) + kk * (BN * 32);
      bf16x8 bfr[4];
#pragma unroll
      for (int n = 0; n < 4; ++n)
        bfr[n] = *(const bf16x8*)(Bb + (wn * 64 + n * 16) * 32 + fragoff);
#pragma unroll
      for (int mg = 0; mg < MG; ++mg) {
        bf16x8 afr[4];
#pragma unroll
        for (int i = 0; i < 4; ++i)
          afr[i] = *(const bf16x8*)(Ab + (wr * (BM / WM) + (mg * 4 + i) * 16) * 32 + fragoff);
        __builtin_amdgcn_s_setprio(1);
#pragma unroll
        for (int i = 0; i < 4; ++i)
#pragma unroll
          for (int n = 0; n < 4; ++n)
            acc[mg * 4 + i][n] =
                __builtin_amdgcn_mfma_f32_16x16x32_bf16(afr[i], bfr[n], acc[mg * 4 + i][n], 0, 0, 0);
        __builtin_amdgcn_s_setprio(0);
      }
    }
  }

  // epilogue
#pragma unroll
  for (int m = 0; m < MF; ++m) {
#pragma unroll
    for (int n = 0; n < 4; ++n) {
#pragma unroll
      for (int rr = 0; rr < 4; ++rr) {
        int row = brow + wr * (BM / WM) + m * 16 + lg * 4 + rr;
        int col = bcol + wn * 64 + n * 16 + lr;
        size_t off = (size_t)row * ldc + col;
        float v = acc[m][n][rr];
        if (EPI == 0) {
          ((float*)Cout)[off] = v;
        } else if (EPI == 1) {
          ((float*)Cout)[off] = Cin[off] + v;
        } else if (EPI == 2) {
          float gv = Cin[off];
          ((__bf16*)Cout)[off] = (__bf16)(gv / (1.f + __expf(-gv)) * v);
        } else {
          ((__bf16*)Cout)[off] = (__bf16)v;
        }
      }
    }
  }
}

// ---------------------------------------------------------------------------
// Rope-on-load helper: chunk d0 (mult of 8, <32) of a 64-wide head slice.
// Produces rotated [d0..d0+7] and [d0+32..d0+39].
// ---------------------------------------------------------------------------
__device__ inline void rope_chunk(const __bf16* p, const float* __restrict__ tab,
                                  int t, int d0, bf16x8& olo, bf16x8& ohi) {
  bf16x8 a8 = *(const bf16x8*)p;
  bf16x8 b8 = *(const bf16x8*)(p + 32);
  const float* ct = tab + t * 32 + d0;
  const float* st = tab + 32768 + t * 32 + d0;
  float4 c0 = *(const float4*)ct, c1 = *(const float4*)(ct + 4);
  float4 s0 = *(const float4*)st, s1 = *(const float4*)(st + 4);
  float cs[8] = {c0.x, c0.y, c0.z, c0.w, c1.x, c1.y, c1.z, c1.w};
  float ss[8] = {s0.x, s0.y, s0.z, s0.w, s1.x, s1.y, s1.z, s1.w};
#pragma unroll
  for (int j = 0; j < 8; ++j) {
    float av = (float)a8[j], bv = (float)b8[j];
    olo[j] = (__bf16)(av * cs[j] - bv * ss[j]);
    ohi[j] = (__bf16)(av * ss[j] + bv * cs[j]);
  }
}

// ---------------------------------------------------------------------------
// Flash attention: qkv bf16 [tok][3072] (q|k|v per head slice), rope fused.
// Block = 64 q-rows x one (b,h). 4 waves x 16 q-rows.
// ---------------------------------------------------------------------------
__global__ __launch_bounds__(256) void attn_kernel(const __bf16* __restrict__ qkv,
                                                   const float* __restrict__ tab,
                                                   __bf16* __restrict__ o) {
  __shared__ __align__(16) __bf16 lsQ[64][72];
  __shared__ __align__(16) __bf16 lsK[64][72];
  __shared__ __align__(16) __bf16 lsVt[64][72];
  __shared__ __align__(16) __bf16 lsP[4][16][72];
  const int tid = threadIdx.x;
  const int lane = tid & 63;
  const int w = tid >> 6;
  const int lr = lane & 15, lg = lane >> 4;
  const int bh = blockIdx.y, b = bh >> 4, h = bh & 15;
  const int q0 = blockIdx.x * 64;
  const size_t base = (size_t)b * T_SEQ * 3072 + h * 64;
  const float scale = 0.125f;

  // stage Q with rope: one pair-chunk per thread
  {
    int row = tid >> 2, pc = tid & 3, d0 = pc * 8;
    int t = q0 + row;
    bf16x8 olo, ohi;
    rope_chunk(qkv + base + (size_t)t * 3072 + d0, tab, t, d0, olo, ohi);
    *(bf16x8*)&lsQ[row][d0] = olo;
    *(bf16x8*)&lsQ[row][d0 + 32] = ohi;
  }

  f32x4 accO[4];
#pragma unroll
  for (int n = 0; n < 4; ++n) accO[n] = (f32x4){0.f, 0.f, 0.f, 0.f};
  float mrow[4], lrow[4];
#pragma unroll
  for (int r = 0; r < 4; ++r) { mrow[r] = -1e30f; lrow[r] = 0.f; }
  const int qw0 = q0 + w * 16;

  for (int j0 = 0; j0 <= q0; j0 += 64) {
    __syncthreads();
    // stage K (rope) and V^T
    {
      int row = tid >> 2, pc = tid & 3, d0 = pc * 8;
      int t = j0 + row;
      bf16x8 olo, ohi;
      rope_chunk(qkv + base + (size_t)t * 3072 + 1024 + d0, tab, t, d0, olo, ohi);
      *(bf16x8*)&lsK[row][d0] = olo;
      *(bf16x8*)&lsK[row][d0 + 32] = ohi;
    }
#pragma unroll
    for (int i = 0; i < 2; ++i) {
      int idx = i * 256 + tid;
      int row = idx >> 3, d0 = (idx & 7) * 8;
      bf16x8 v8 = *(const bf16x8*)(qkv + base + (size_t)(j0 + row) * 3072 + 2048 + d0);
#pragma unroll
      for (int j = 0; j < 8; ++j) lsVt[d0 + j][row] = v8[j];
    }
    __syncthreads();

    f32x4 s4[4];
#pragma unroll
    for (int n = 0; n < 4; ++n) s4[n] = (f32x4){0.f, 0.f, 0.f, 0.f};
#pragma unroll
    for (int kk = 0; kk < 2; ++kk) {
      bf16x8 aq = *(bf16x8*)&lsQ[w * 16 + lr][kk * 32 + lg * 8];
#pragma unroll
      for (int n = 0; n < 4; ++n) {
        bf16x8 bk = *(bf16x8*)&lsK[n * 16 + lr][kk * 32 + lg * 8];
        s4[n] = __builtin_amdgcn_mfma_f32_16x16x32_bf16(aq, bk, s4[n], 0, 0, 0);
      }
    }

    float pm[4];
#pragma unroll
    for (int r = 0; r < 4; ++r) pm[r] = -1e30f;
#pragma unroll
    for (int n = 0; n < 4; ++n) {
      int gj = j0 + n * 16 + lr;
#pragma unroll
      for (int r = 0; r < 4; ++r) {
        int gq = qw0 + lg * 4 + r;
        float sv = s4[n][r] * scale;
        if (gj > gq) sv = -1e30f;
        s4[n][r] = sv;
        pm[r] = fmaxf(pm[r], sv);
      }
    }
#pragma unroll
    for (int r = 0; r < 4; ++r) {
#pragma unroll
      for (int m = 8; m >= 1; m >>= 1) pm[r] = fmaxf(pm[r], __shfl_xor(pm[r], m, 64));
    }
    float alpha[4];
#pragma unroll
    for (int r = 0; r < 4; ++r) {
      float mn = fmaxf(mrow[r], pm[r]);
      alpha[r] = expf(mrow[r] - mn);
      mrow[r] = mn;
    }
    float ps[4] = {0.f, 0.f, 0.f, 0.f};
#pragma unroll
    for (int n = 0; n < 4; ++n) {
#pragma unroll
      for (int r = 0; r < 4; ++r) {
        float p = expf(s4[n][r] - mrow[r]);
        s4[n][r] = p;
        ps[r] += p;
      }
    }
#pragma unroll
    for (int r = 0; r < 4; ++r) {
#pragma unroll
      for (int m = 8; m >= 1; m >>= 1) ps[r] += __shfl_xor(ps[r], m, 64);
      lrow[r] = lrow[r] * alpha[r] + ps[r];
    }
#pragma unroll
    for (int n = 0; n < 4; ++n) {
#pragma unroll
      for (int r = 0; r < 4; ++r) accO[n][r] *= alpha[r];
    }
#pragma unroll
    for (int n = 0; n < 4; ++n) {
#pragma unroll
      for (int r = 0; r < 4; ++r) lsP[w][lg * 4 + r][n * 16 + lr] = (__bf16)s4[n][r];
    }
    asm volatile("s_waitcnt lgkmcnt(0)" ::: "memory");
    __builtin_amdgcn_sched_barrier(0);
#pragma unroll
    for (int kk = 0; kk < 2; ++kk) {
      bf16x8 ap = *(bf16x8*)&lsP[w][lr][kk * 32 + lg * 8];
#pragma unroll
      for (int n = 0; n < 4; ++n) {
        bf16x8 bv = *(bf16x8*)&lsVt[n * 16 + lr][kk * 32 + lg * 8];
        accO[n] = __builtin_amdgcn_mfma_f32_16x16x32_bf16(ap, bv, accO[n], 0, 0, 0);
      }
    }
  }

#pragma unroll
  for (int n = 0; n < 4; ++n) {
#pragma unroll
    for (int r = 0; r < 4; ++r) {
      int gq = qw0 + lg * 4 + r;
      float val = accO[n][r] / lrow[r];
      o[(size_t)(b * T_SEQ + gq) * D_MODEL + h * 64 + n * 16 + lr] = (__bf16)val;
    }
  }
}

// ---------------------------------------------------------------------------
extern "C" void kernel_launch(void* const* d_in, const int* in_sizes, int n_in,
                              void* d_out, int out_size, void* d_ws, size_t ws_size,
                              hipStream_t stream) {
  const int*   idx     = (const int*)d_in[0];
  const float* W_emb   = (const float*)d_in[1];
  const float* norm1_w = (const float*)d_in[2];
  const float* Wqkv    = (const float*)d_in[3];
  const float* Wout    = (const float*)d_in[4];
  const float* norm2_w = (const float*)d_in[5];
  const float* Wg      = (const float*)d_in[6];
  const float* Wu      = (const float*)d_in[7];
  const float* Wd      = (const float*)d_in[8];
  const float* fnorm   = (const float*)d_in[9];
  float* out = (float*)d_out;

  // workspace layout
  float*  x    = (float*)d_ws;                              // 2048*1024 f32
  float*  g    = x + (size_t)NTOK * D_MODEL;                // 2048*2816 f32
  float*  tab  = g + (size_t)NTOK * HID_PAD;                // 2*32768 f32
  __bf16* qkvb = (__bf16*)(tab + 2 * 32768);                // 2048*3072 bf16
  __bf16* hb   = qkvb + (size_t)NTOK * 3 * D_MODEL;         // 2048*1024 bf16
  __bf16* ob   = hb + (size_t)NTOK * D_MODEL;               // 2048*1024 bf16
  __bf16* ga   = ob + (size_t)NTOK * D_MODEL;               // 2048*2816 bf16
  __bf16* wbuf = ga + (size_t)NTOK * HID_PAD;               // up to 32.77M bf16

  __bf16* wqkvT = wbuf;                                     // [3072][1024]
  __bf16* woutT = wqkvT + (size_t)3 * D_MODEL * D_MODEL;    // [1024][1024]
  __bf16* wgT   = woutT + (size_t)D_MODEL * D_MODEL;        // [2816][1024]
  __bf16* wuT   = wgT + (size_t)HID_PAD * D_MODEL;          // [2816][1024]
  __bf16* wdT   = wuT + (size_t)HID_PAD * D_MODEL;          // [1024][2816]

  embed_kernel<<<NTOK, 256, 0, stream>>>(idx, W_emb, x);
  rope_table_kernel<<<128, 256, 0, stream>>>(tab);

  for (int l = 0; l < NLAYER; ++l) {
    transpose_bf16_kernel<<<dim3(16, 48), 256, 0, stream>>>(
        Wqkv + (size_t)l * D_MODEL * 3 * D_MODEL, wqkvT, D_MODEL, 3 * D_MODEL, D_MODEL);
    transpose_bf16_kernel<<<dim3(16, 16), 256, 0, stream>>>(
        Wout + (size_t)l * D_MODEL * D_MODEL, woutT, D_MODEL, D_MODEL, D_MODEL);
    transpose_bf16_kernel<<<dim3(16, 44), 256, 0, stream>>>(
        Wg + (size_t)l * D_MODEL * HID, wgT, D_MODEL, HID, D_MODEL);
    transpose_bf16_kernel<<<dim3(16, 44), 256, 0, stream>>>(
        Wu + (size_t)l * D_MODEL * HID, wuT, D_MODEL, HID, D_MODEL);
    transpose_bf16_kernel<<<dim3(44, 16), 256, 0, stream>>>(
        Wd + (size_t)l * HID * D_MODEL, wdT, HID, D_MODEL, HID_PAD);

    rmsnorm_kernel<<<NTOK, 256, 0, stream>>>(x, norm1_w + (size_t)l * D_MODEL, hb);
    gemm8<256, 256, 2, 4, 3><<<dim3(8, 12), 512, 0, stream>>>(
        hb, wqkvT, nullptr, qkvb, D_MODEL, 3 * D_MODEL);
    attn_kernel<<<dim3(16, 32), 256, 0, stream>>>(qkvb, tab, ob);
    gemm8<128, 128, 2, 2, 1><<<dim3(16, 8), 256, 0, stream>>>(
        ob, woutT, x, x, D_MODEL, D_MODEL);
    rmsnorm_kernel<<<NTOK, 256, 0, stream>>>(x, norm2_w + (size_t)l * D_MODEL, hb);
    gemm8<256, 256, 2, 4, 0><<<dim3(8, 11), 512, 0, stream>>>(
        hb, wgT, nullptr, g, D_MODEL, HID_PAD);
    gemm8<256, 256, 2, 4, 2><<<dim3(8, 11), 512, 0, stream>>>(
        hb, wuT, g, ga, D_MODEL, HID_PAD);
    gemm8<128, 128, 2, 2, 1><<<dim3(16, 8), 256, 0, stream>>>(
        ga, wdT, x, x, HID_PAD, D_MODEL);
  }

  rmsnorm_kernel<<<NTOK, 256, 0, stream>>>(x, fnorm, hb);
  convert_bf16_kernel<<<2048, 256, 0, stream>>>(W_emb, wbuf, VOCAB * D_MODEL / 4);
  gemm8<256, 256, 2, 4, 0><<<dim3(8, 125), 512, 0, stream>>>(
      hb, wbuf, nullptr, out, D_MODEL, VOCAB);
}

// Round 4
// 2104.021 us; speedup vs baseline: 3.9811x; 1.1736x over previous
//
#include <hip/hip_runtime.h>
#include <cstdint>
#include <cmath>

#define D_MODEL 1024
#define T_SEQ   1024
#define NHEAD   16
#define NLAYER  8
#define HID     2734
#define HID_PAD 2816
#define NTOK    2048
#define VOCAB   32000

typedef __bf16 bf16x8 __attribute__((ext_vector_type(8)));
typedef __bf16 bf16x4 __attribute__((ext_vector_type(4)));
typedef float  f32x4  __attribute__((ext_vector_type(4)));

__device__ inline bf16x4 to_bf4(float a, float b, float c, float d) {
  bf16x4 t; t[0] = (__bf16)a; t[1] = (__bf16)b; t[2] = (__bf16)c; t[3] = (__bf16)d; return t;
}

__device__ inline void gload16(const __bf16* g, __bf16* l) {
  __builtin_amdgcn_global_load_lds(
      (const __attribute__((address_space(1))) void*)g,
      (__attribute__((address_space(3))) void*)l, 16, 0, 0);
}

// ---------------------------------------------------------------------------
// Embedding gather
// ---------------------------------------------------------------------------
__global__ __launch_bounds__(256) void embed_kernel(const int* __restrict__ idx,
                                                    const float* __restrict__ W,
                                                    float* __restrict__ x) {
  int t = blockIdx.x;
  int v = idx[t];
  float4 val = *(const float4*)&W[(size_t)v * D_MODEL + threadIdx.x * 4];
  *(float4*)&x[(size_t)t * D_MODEL + threadIdx.x * 4] = val;
}

// ---------------------------------------------------------------------------
// RMSNorm: f32 in -> bf16 out
// ---------------------------------------------------------------------------
__global__ __launch_bounds__(256) void rmsnorm_kernel(const float* __restrict__ x,
                                                      const float* __restrict__ w,
                                                      __bf16* __restrict__ out) {
  int row = blockIdx.x;
  int tid = threadIdx.x;
  float4 v = *(const float4*)&x[(size_t)row * D_MODEL + tid * 4];
  float s = v.x * v.x + v.y * v.y + v.z * v.z + v.w * v.w;
#pragma unroll
  for (int m = 32; m >= 1; m >>= 1) s += __shfl_xor(s, m, 64);
  __shared__ float red[4];
  if ((tid & 63) == 0) red[tid >> 6] = s;
  __syncthreads();
  float tot = red[0] + red[1] + red[2] + red[3];
  float inv = rsqrtf(tot * (1.0f / (float)D_MODEL) + 1e-6f);
  float4 wv = *(const float4*)&w[tid * 4];
  bf16x4 o4 = to_bf4(v.x * inv * wv.x, v.y * inv * wv.y, v.z * inv * wv.z, v.w * inv * wv.w);
  *(bf16x4*)&out[(size_t)row * D_MODEL + tid * 4] = o4;
}

// ---------------------------------------------------------------------------
// RoPE cos/sin table
// ---------------------------------------------------------------------------
__global__ __launch_bounds__(256) void rope_table_kernel(float* __restrict__ tab) {
  int p = blockIdx.x * 256 + threadIdx.x;
  int t = p >> 5, i = p & 31;
  float freq = exp2f(-(float)i * (13.287712379549449f / 32.0f));
  float sn, cs;
  sincosf((float)t * freq, &sn, &cs);
  tab[p] = cs;
  tab[32768 + p] = sn;
}

// ---------------------------------------------------------------------------
// Transpose + convert: in f32 [R][C] -> out bf16 rows (c*rmul+roff), cols [Ro].
// ---------------------------------------------------------------------------
__global__ __launch_bounds__(256) void transpose_bf16_kernel(
    const float* __restrict__ in, __bf16* __restrict__ out,
    int R, int C, int Ro, int rmul, int roff) {
  __shared__ __bf16 tile[64][65];
  int r0 = blockIdx.x * 64, c0 = blockIdx.y * 64;
  int tid = threadIdx.x;
  bool fullc = (c0 + 64 <= C);
#pragma unroll
  for (int i = 0; i < 4; ++i) {
    int ri = i * 16 + (tid >> 4);
    int ci = (tid & 15) * 4;
    int r = r0 + ri;
    float4 v = {0.f, 0.f, 0.f, 0.f};
    if (r < R) {
      const float* p = in + (size_t)r * C + c0 + ci;
      if (fullc) {
        v = *(const float4*)p;
      } else {
        int c = c0 + ci;
        if (c + 0 < C) v.x = p[0];
        if (c + 1 < C) v.y = p[1];
        if (c + 2 < C) v.z = p[2];
        if (c + 3 < C) v.w = p[3];
      }
    }
    tile[ri][ci + 0] = (__bf16)v.x;
    tile[ri][ci + 1] = (__bf16)v.y;
    tile[ri][ci + 2] = (__bf16)v.z;
    tile[ri][ci + 3] = (__bf16)v.w;
  }
  __syncthreads();
#pragma unroll
  for (int i = 0; i < 4; ++i) {
    int oc = i * 16 + (tid >> 4);
    int orr = (tid & 15) * 4;
    bf16x4 t;
    t[0] = tile[orr + 0][oc];
    t[1] = tile[orr + 1][oc];
    t[2] = tile[orr + 2][oc];
    t[3] = tile[orr + 3][oc];
    *(bf16x4*)&out[((size_t)(c0 + oc) * rmul + roff) * Ro + r0 + orr] = t;
  }
}

// ---------------------------------------------------------------------------
// Plain f32 -> bf16 convert
// ---------------------------------------------------------------------------
__global__ __launch_bounds__(256) void convert_bf16_kernel(const float* __restrict__ in,
                                                           __bf16* __restrict__ out, int n4) {
  for (int i = blockIdx.x * 256 + threadIdx.x; i < n4; i += gridDim.x * 256) {
    float4 v = ((const float4*)in)[i];
    ((bf16x4*)out)[i] = to_bf4(v.x, v.y, v.z, v.w);
  }
}

// ---------------------------------------------------------------------------
// 8-phase deep-pipelined GEMM: C[M,N] = A[M,K] @ B^T, sigma-permuted LDS chunks,
// counted vmcnt, setprio. EPI: 0 f32, 1 f32+residual, 2 bf16 silu(Cin)*acc,
// 3 bf16 plain, 4 interleaved-g/u fused silu (bf16, cols halved).
// ---------------------------------------------------------------------------
template <int BM, int BN, int WM, int WN, int EPI>
__global__ __launch_bounds__(WM * WN * 64, 2) void gemm8(
    const __bf16* __restrict__ A, const __bf16* __restrict__ B,
    const float* __restrict__ Cin, void* __restrict__ Cout,
    int K, int ldc) {
  constexpr int NTH = WM * WN * 64;
  constexpr int MF = BM / (16 * WM);
  constexpr int MG = (MF + 3) / 4;
  constexpr int LA = (BM * 4) / NTH;
  constexpr int LB = (BN * 4) / NTH;
  static_assert(BN / WN == 64, "NF must be 4");
  __shared__ __align__(16) __bf16 lds[(BM + BN) * 128];

  const int tid = threadIdx.x;
  const int lane = tid & 63, wid = tid >> 6;
  const int wr = wid / WN, wn = wid % WN;
  const int lr = lane & 15, lg = lane >> 4;

  const int gx = gridDim.x;
  const int nwg = gx * gridDim.y;
  const int orig = blockIdx.y * gx + blockIdx.x;
  const int q = nwg >> 3, r8 = nwg & 7;
  const int xcd = orig & 7, loc = orig >> 3;
  const int swz = ((xcd < r8) ? xcd * (q + 1) : r8 * (q + 1) + (xcd - r8) * q) + loc;
  const int brow = (swz % gx) * BM;
  const int bcol = (swz / gx) * BN;

  const __bf16* pAg[LA];
  const __bf16* pBg[LB];
  int opA[LA], opB[LB];
#pragma unroll
  for (int i = 0; i < LA; ++i) {
    int p = tid + i * NTH;
    int row = ((p >> 6) << 4) | (p & 15), j = (p >> 4) & 3;
    pAg[i] = A + (size_t)(brow + row) * K + j * 8;
    opA[i] = p * 8;
  }
#pragma unroll
  for (int i = 0; i < LB; ++i) {
    int p = tid + i * NTH;
    int row = ((p >> 6) << 4) | (p & 15), j = (p >> 4) & 3;
    pBg[i] = B + (size_t)(bcol + row) * K + j * 8;
    opB[i] = p * 8;
  }

  const int ntiles = K >> 6;

  auto STAGE = [&](int v, int kkq) {
    int vs = v < ntiles ? v : ntiles - 1;
    int ko = vs * 64 + kkq * 32;
    int sa = (v & 1) * (BM * 64) + kkq * (BM * 32);
    int sb = BM * 128 + (v & 1) * (BN * 64) + kkq * (BN * 32);
#pragma unroll
    for (int i = 0; i < LA; ++i) gload16(pAg[i] + ko, lds + sa + opA[i]);
#pragma unroll
    for (int i = 0; i < LB; ++i) gload16(pBg[i] + ko, lds + sb + opB[i]);
  };

  f32x4 acc[MF][4];
#pragma unroll
  for (int m = 0; m < MF; ++m)
#pragma unroll
    for (int n = 0; n < 4; ++n) acc[m][n] = (f32x4){0.f, 0.f, 0.f, 0.f};

  STAGE(0, 0);
  STAGE(0, 1);
  STAGE(1, 0);

  const int fragoff = lg * 128 + lr * 8;

  for (int u = 0; u < ntiles; ++u) {
    const int buf = u & 1;
#pragma unroll
    for (int kk = 0; kk < 2; ++kk) {
      if constexpr (LA + LB == 3) asm volatile("s_waitcnt vmcnt(6)" ::: "memory");
      else                        asm volatile("s_waitcnt vmcnt(8)" ::: "memory");
      __builtin_amdgcn_sched_barrier(0);
      __builtin_amdgcn_s_barrier();
      __builtin_amdgcn_sched_barrier(0);
      if (kk == 0) STAGE(u + 1, 1);
      else         STAGE(u + 2, 0);
      const __bf16* Ab = lds + buf * (BM * 64) + kk * (BM * 32);
      const __bf16* Bb = lds + BM * 128 + buf * (BN * 64) + kk * (BN * 32);
      bf16x8 bfr[4];
#pragma unroll
      for (int n = 0; n < 4; ++n)
        bfr[n] = *(const bf16x8*)(Bb + (wn * 64 + n * 16) * 32 + fragoff);
#pragma unroll
      for (int mg = 0; mg < MG; ++mg) {
        bf16x8 afr[4];
#pragma unroll
        for (int i = 0; i < 4; ++i)
          afr[i] = *(const bf16x8*)(Ab + (wr * (BM / WM) + (mg * 4 + i) * 16) * 32 + fragoff);
        __builtin_amdgcn_s_setprio(1);
#pragma unroll
        for (int i = 0; i < 4; ++i)
#pragma unroll
          for (int n = 0; n < 4; ++n)
            acc[mg * 4 + i][n] =
                __builtin_amdgcn_mfma_f32_16x16x32_bf16(afr[i], bfr[n], acc[mg * 4 + i][n], 0, 0, 0);
        __builtin_amdgcn_s_setprio(0);
      }
    }
  }

#pragma unroll
  for (int m = 0; m < MF; ++m) {
#pragma unroll
    for (int n = 0; n < 4; ++n) {
#pragma unroll
      for (int rr = 0; rr < 4; ++rr) {
        int row = brow + wr * (BM / WM) + m * 16 + lg * 4 + rr;
        int col = bcol + wn * 64 + n * 16 + lr;
        size_t off = (size_t)row * ldc + col;
        float v = acc[m][n][rr];
        if (EPI == 0) {
          ((float*)Cout)[off] = v;
        } else if (EPI == 1) {
          ((float*)Cout)[off] = Cin[off] + v;
        } else if (EPI == 2) {
          float gv = Cin[off];
          ((__bf16*)Cout)[off] = (__bf16)(gv / (1.f + __expf(-gv)) * v);
        } else if (EPI == 3) {
          ((__bf16*)Cout)[off] = (__bf16)v;
        } else {
          float uv = __shfl_xor(v, 1);
          if ((lr & 1) == 0) {
            float r = v / (1.f + __expf(-v)) * uv;
            ((__bf16*)Cout)[(size_t)row * ldc + (col >> 1)] = (__bf16)r;
          }
        }
      }
    }
  }
}

// ---------------------------------------------------------------------------
// Rope helper (8-wide pair chunk)
// ---------------------------------------------------------------------------
__device__ inline void rope_chunk(const __bf16* p, const float* __restrict__ tab,
                                  int t, int d0, bf16x8& olo, bf16x8& ohi) {
  bf16x8 a8 = *(const bf16x8*)p;
  bf16x8 b8 = *(const bf16x8*)(p + 32);
  const float* ct = tab + t * 32 + d0;
  const float* st = tab + 32768 + t * 32 + d0;
  float4 c0 = *(const float4*)ct, c1 = *(const float4*)(ct + 4);
  float4 s0 = *(const float4*)st, s1 = *(const float4*)(st + 4);
  float cs[8] = {c0.x, c0.y, c0.z, c0.w, c1.x, c1.y, c1.z, c1.w};
  float ss[8] = {s0.x, s0.y, s0.z, s0.w, s1.x, s1.y, s1.z, s1.w};
#pragma unroll
  for (int j = 0; j < 8; ++j) {
    float av = (float)a8[j], bv = (float)b8[j];
    olo[j] = (__bf16)(av * cs[j] - bv * ss[j]);
    ohi[j] = (__bf16)(av * ss[j] + bv * cs[j]);
  }
}

// ---------------------------------------------------------------------------
// prep: per (b,h, 64-token block): rope(q)->Qr, rope(k)->Kr, v^T -> Vt.
// Qr/Kr: [bh][t][64]; Vt: [bh][64][1024].
// ---------------------------------------------------------------------------
__global__ __launch_bounds__(256) void prep_kernel(const __bf16* __restrict__ qkv,
                                                   const float* __restrict__ tab,
                                                   __bf16* __restrict__ Qr,
                                                   __bf16* __restrict__ Kr,
                                                   __bf16* __restrict__ Vt) {
  __shared__ __bf16 lsV[64][72];
  const int tid = threadIdx.x;
  const int bh = blockIdx.y, b = bh >> 4, h = bh & 15;
  const int t0 = blockIdx.x * 64;
  const size_t qbase = (size_t)b * T_SEQ * 3072 + h * 64;

  int row = tid >> 2, pc = tid & 3;
  int t = t0 + row;
  int tl = t & 1023;
  {
    int d0 = pc * 8;
    bf16x8 olo, ohi;
    rope_chunk(qkv + qbase + (size_t)t * 3072 + d0, tab, tl, d0, olo, ohi);
    __bf16* qo = Qr + ((size_t)bh * T_SEQ + t) * 64;
    *(bf16x8*)(qo + d0) = olo;
    *(bf16x8*)(qo + d0 + 32) = ohi;
    rope_chunk(qkv + qbase + (size_t)t * 3072 + 1024 + d0, tab, tl, d0, olo, ohi);
    __bf16* ko = Kr + ((size_t)bh * T_SEQ + t) * 64;
    *(bf16x8*)(ko + d0) = olo;
    *(bf16x8*)(ko + d0 + 32) = ohi;
  }
  {
    int c = pc * 16;
    bf16x8 v0 = *(const bf16x8*)(qkv + qbase + (size_t)t * 3072 + 2048 + c);
    bf16x8 v1 = *(const bf16x8*)(qkv + qbase + (size_t)t * 3072 + 2048 + c + 8);
    *(bf16x8*)&lsV[row][c] = v0;
    *(bf16x8*)&lsV[row][c + 8] = v1;
  }
  __syncthreads();
  {
    int d = tid >> 2, tc = (tid & 3) * 16;
    bf16x8 o0, o1;
#pragma unroll
    for (int j = 0; j < 8; ++j) o0[j] = lsV[tc + j][d];
#pragma unroll
    for (int j = 0; j < 8; ++j) o1[j] = lsV[tc + 8 + j][d];
    __bf16* vo = Vt + ((size_t)bh * 64 + d) * T_SEQ + t0 + tc;
    *(bf16x8*)vo = o0;
    *(bf16x8*)(vo + 8) = o1;
  }
}

// ---------------------------------------------------------------------------
// Flash attention v2: Q/K/Vt staged via global_load_lds into sigma layout.
// Block = 64 q-rows x one (b,h), 4 waves x 16 q-rows, KVBLK=128.
// LDS map (bf16 elements): Q[2 slots][2048] @0, K[2][4096] @4096,
// Vt[4][2048] @12288, P[4 waves][4 slots][512] @20480. Total 28672 el = 56KB.
// ---------------------------------------------------------------------------
__global__ __launch_bounds__(256) void attn_kernel(const __bf16* __restrict__ Qr,
                                                   const __bf16* __restrict__ Kr,
                                                   const __bf16* __restrict__ Vt,
                                                   __bf16* __restrict__ o) {
  __shared__ __align__(16) __bf16 lds[28672];
  const int tid = threadIdx.x;
  const int lane = tid & 63, w = tid >> 6;
  const int lr = lane & 15, lg = lane >> 4;
  const int bh = blockIdx.y, b = bh >> 4, h = bh & 15;
  const int qb = blockIdx.x, q0 = qb * 64;
  const __bf16* Qg = Qr + ((size_t)bh * T_SEQ + q0) * 64;
  const __bf16* Kg = Kr + (size_t)bh * T_SEQ * 64;
  const __bf16* Vg = Vt + (size_t)bh * 64 * T_SEQ;
  const float scale = 0.125f;

  // Q stage (one chunk per slot per thread)
  {
    int row = ((tid >> 6) << 4) | (tid & 15);
    int j = (tid >> 4) & 3;
    gload16(Qg + row * 64 + j * 8, lds + tid * 8);
    gload16(Qg + row * 64 + 32 + j * 8, lds + 2048 + tid * 8);
  }

  f32x4 accO[4];
#pragma unroll
  for (int n = 0; n < 4; ++n) accO[n] = (f32x4){0.f, 0.f, 0.f, 0.f};
  float mrow[4], lrow[4];
#pragma unroll
  for (int r = 0; r < 4; ++r) { mrow[r] = -1e30f; lrow[r] = 0.f; }

  const int ntile = ((q0 + 63) >> 7) + 1;
  __bf16* Pw = lds + 20480 + w * 2048;

  for (int tt = 0; tt < ntile; ++tt) {
    const int j0 = tt * 128;
    __syncthreads();
    // stage K: 2 slots x 512 chunks
#pragma unroll
    for (int i = 0; i < 2; ++i) {
      int p = tid + i * 256;
      int row = ((p >> 6) << 4) | (p & 15), j = (p >> 4) & 3;
      const __bf16* src = Kg + (size_t)(j0 + row) * 64 + j * 8;
      gload16(src, lds + 4096 + p * 8);
      gload16(src + 32, lds + 8192 + p * 8);
    }
    // stage Vt: 4 slots x 256 chunks
#pragma unroll
    for (int s = 0; s < 4; ++s) {
      int d = ((tid >> 6) << 4) | (tid & 15), j = (tid >> 4) & 3;
      gload16(Vg + (size_t)d * T_SEQ + j0 + s * 32 + j * 8, lds + 12288 + s * 2048 + tid * 8);
    }
    __syncthreads();

    // QK^T: 8 j-frags x 2 kk
    f32x4 s4[8];
#pragma unroll
    for (int n = 0; n < 8; ++n) s4[n] = (f32x4){0.f, 0.f, 0.f, 0.f};
#pragma unroll
    for (int kk = 0; kk < 2; ++kk) {
      bf16x8 aq = *(const bf16x8*)(lds + kk * 2048 + (w * 64 + lg * 16 + lr) * 8);
      __builtin_amdgcn_s_setprio(1);
#pragma unroll
      for (int jf = 0; jf < 8; ++jf) {
        bf16x8 bk = *(const bf16x8*)(lds + 4096 + kk * 4096 + (jf * 64 + lg * 16 + lr) * 8);
        s4[jf] = __builtin_amdgcn_mfma_f32_16x16x32_bf16(aq, bk, s4[jf], 0, 0, 0);
      }
      __builtin_amdgcn_s_setprio(0);
    }

    // scale + causal + row max
    float pm[4];
#pragma unroll
    for (int r = 0; r < 4; ++r) pm[r] = -1e30f;
#pragma unroll
    for (int jf = 0; jf < 8; ++jf) {
      int gj = j0 + jf * 16 + lr;
#pragma unroll
      for (int r = 0; r < 4; ++r) {
        int gq = q0 + w * 16 + lg * 4 + r;
        float sv = s4[jf][r] * scale;
        if (gj > gq) sv = -1e30f;
        s4[jf][r] = sv;
        pm[r] = fmaxf(pm[r], sv);
      }
    }
#pragma unroll
    for (int r = 0; r < 4; ++r) {
#pragma unroll
      for (int m = 8; m >= 1; m >>= 1) pm[r] = fmaxf(pm[r], __shfl_xor(pm[r], m, 64));
    }
    float alpha[4];
#pragma unroll
    for (int r = 0; r < 4; ++r) {
      float mn = fmaxf(mrow[r], pm[r]);
      alpha[r] = expf(mrow[r] - mn);
      mrow[r] = mn;
    }
    float ps[4] = {0.f, 0.f, 0.f, 0.f};
#pragma unroll
    for (int jf = 0; jf < 8; ++jf) {
#pragma unroll
      for (int r = 0; r < 4; ++r) {
        float p = expf(s4[jf][r] - mrow[r]);
        s4[jf][r] = p;
        ps[r] += p;
      }
    }
#pragma unroll
    for (int r = 0; r < 4; ++r) {
#pragma unroll
      for (int m = 8; m >= 1; m >>= 1) ps[r] += __shfl_xor(ps[r], m, 64);
      lrow[r] = lrow[r] * alpha[r] + ps[r];
    }
#pragma unroll
    for (int n = 0; n < 4; ++n) {
#pragma unroll
      for (int r = 0; r < 4; ++r) accO[n][r] *= alpha[r];
    }

    // P -> LDS sigma layout (per wave)
#pragma unroll
    for (int jf = 0; jf < 8; ++jf) {
      int s = jf >> 1;
      int rem = ((jf & 1) << 4) + lr;
      int base = s * 512 + (rem >> 3) * 128 + (rem & 7);
#pragma unroll
      for (int r = 0; r < 4; ++r) {
        int qloc = lg * 4 + r;
        Pw[base + qloc * 8] = (__bf16)s4[jf][r];
      }
    }
    asm volatile("s_waitcnt lgkmcnt(0)" ::: "memory");
    __builtin_amdgcn_sched_barrier(0);

    // PV: 4 kv-slots x 4 d-frags
#pragma unroll
    for (int s = 0; s < 4; ++s) {
      bf16x8 pa = *(const bf16x8*)(Pw + s * 512 + (lg * 16 + lr) * 8);
      __builtin_amdgcn_s_setprio(1);
#pragma unroll
      for (int nd = 0; nd < 4; ++nd) {
        bf16x8 bv = *(const bf16x8*)(lds + 12288 + s * 2048 + (nd * 64 + lg * 16 + lr) * 8);
        accO[nd] = __builtin_amdgcn_mfma_f32_16x16x32_bf16(pa, bv, accO[nd], 0, 0, 0);
      }
      __builtin_amdgcn_s_setprio(0);
    }
  }

  // write O (bf16)
#pragma unroll
  for (int nd = 0; nd < 4; ++nd) {
#pragma unroll
    for (int r = 0; r < 4; ++r) {
      int gq = q0 + w * 16 + lg * 4 + r;
      float val = accO[nd][r] / lrow[r];
      o[(size_t)(b * T_SEQ + gq) * D_MODEL + h * 64 + nd * 16 + lr] = (__bf16)val;
    }
  }
}

// ---------------------------------------------------------------------------
extern "C" void kernel_launch(void* const* d_in, const int* in_sizes, int n_in,
                              void* d_out, int out_size, void* d_ws, size_t ws_size,
                              hipStream_t stream) {
  const int*   idx     = (const int*)d_in[0];
  const float* W_emb   = (const float*)d_in[1];
  const float* norm1_w = (const float*)d_in[2];
  const float* Wqkv    = (const float*)d_in[3];
  const float* Wout    = (const float*)d_in[4];
  const float* norm2_w = (const float*)d_in[5];
  const float* Wg      = (const float*)d_in[6];
  const float* Wu      = (const float*)d_in[7];
  const float* Wd      = (const float*)d_in[8];
  const float* fnorm   = (const float*)d_in[9];
  float* out = (float*)d_out;

  float*  x    = (float*)d_ws;                              // 2048*1024 f32
  float*  tab  = x + (size_t)NTOK * D_MODEL;                // 2*32768 f32
  __bf16* qkvb = (__bf16*)(tab + 2 * 32768);                // 2048*3072
  __bf16* hb   = qkvb + (size_t)NTOK * 3 * D_MODEL;         // 2048*1024
  __bf16* ob   = hb + (size_t)NTOK * D_MODEL;               // 2048*1024
  __bf16* ga   = ob + (size_t)NTOK * D_MODEL;               // 2048*2816
  __bf16* Qrb  = ga + (size_t)NTOK * HID_PAD;               // 32*1024*64
  __bf16* Krb  = Qrb + (size_t)32 * T_SEQ * 64;
  __bf16* Vtb  = Krb + (size_t)32 * T_SEQ * 64;
  __bf16* wbuf = Vtb + (size_t)32 * T_SEQ * 64;             // up to 32.77M

  __bf16* wqkvT = wbuf;                                     // [3072][1024]
  __bf16* woutT = wqkvT + (size_t)3 * D_MODEL * D_MODEL;    // [1024][1024]
  __bf16* wguT  = woutT + (size_t)D_MODEL * D_MODEL;        // [5632][1024]
  __bf16* wdT   = wguT + (size_t)2 * HID_PAD * D_MODEL;     // [1024][2816]

  embed_kernel<<<NTOK, 256, 0, stream>>>(idx, W_emb, x);
  rope_table_kernel<<<128, 256, 0, stream>>>(tab);

  for (int l = 0; l < NLAYER; ++l) {
    transpose_bf16_kernel<<<dim3(16, 48), 256, 0, stream>>>(
        Wqkv + (size_t)l * D_MODEL * 3 * D_MODEL, wqkvT, D_MODEL, 3 * D_MODEL, D_MODEL, 1, 0);
    transpose_bf16_kernel<<<dim3(16, 16), 256, 0, stream>>>(
        Wout + (size_t)l * D_MODEL * D_MODEL, woutT, D_MODEL, D_MODEL, D_MODEL, 1, 0);
    transpose_bf16_kernel<<<dim3(16, 44), 256, 0, stream>>>(
        Wg + (size_t)l * D_MODEL * HID, wguT, D_MODEL, HID, D_MODEL, 2, 0);
    transpose_bf16_kernel<<<dim3(16, 44), 256, 0, stream>>>(
        Wu + (size_t)l * D_MODEL * HID, wguT, D_MODEL, HID, D_MODEL, 2, 1);
    transpose_bf16_kernel<<<dim3(44, 16), 256, 0, stream>>>(
        Wd + (size_t)l * HID * D_MODEL, wdT, HID, D_MODEL, HID_PAD, 1, 0);

    rmsnorm_kernel<<<NTOK, 256, 0, stream>>>(x, norm1_w + (size_t)l * D_MODEL, hb);
    gemm8<128, 256, 2, 4, 3><<<dim3(16, 12), 512, 0, stream>>>(
        hb, wqkvT, nullptr, qkvb, D_MODEL, 3 * D_MODEL);
    prep_kernel<<<dim3(16, 32), 256, 0, stream>>>(qkvb, tab, Qrb, Krb, Vtb);
    attn_kernel<<<dim3(16, 32), 256, 0, stream>>>(Qrb, Krb, Vtb, ob);
    gemm8<128, 128, 2, 2, 1><<<dim3(16, 8), 256, 0, stream>>>(
        ob, woutT, x, x, D_MODEL, D_MODEL);
    rmsnorm_kernel<<<NTOK, 256, 0, stream>>>(x, norm2_w + (size_t)l * D_MODEL, hb);
    gemm8<128, 256, 2, 4, 4><<<dim3(16, 22), 512, 0, stream>>>(
        hb, wguT, nullptr, ga, D_MODEL, HID_PAD);
    gemm8<128, 128, 2, 2, 1><<<dim3(16, 8), 256, 0, stream>>>(
        ga, wdT, x, x, HID_PAD, D_MODEL);
  }

  rmsnorm_kernel<<<NTOK, 256, 0, stream>>>(x, fnorm, hb);
  convert_bf16_kernel<<<2048, 256, 0, stream>>>(W_emb, wbuf, VOCAB * D_MODEL / 4);
  gemm8<256, 256, 2, 4, 0><<<dim3(8, 125), 512, 0, stream>>>(
      hb, wbuf, nullptr, out, D_MODEL, VOCAB);
}

// Round 6
// 1779.623 us; speedup vs baseline: 4.7068x; 1.1823x over previous
//
#include <hip/hip_runtime.h>
#include <cstdint>
#include <cmath>

#define D_MODEL 1024
#define T_SEQ   1024
#define NHEAD   16
#define NLAYER  8
#define HID     2734
#define HID_PAD 2816
#define NTOK    2048
#define VOCAB   32000

typedef __bf16 bf16x8 __attribute__((ext_vector_type(8)));
typedef __bf16 bf16x4 __attribute__((ext_vector_type(4)));
typedef float  f32x4  __attribute__((ext_vector_type(4)));

__device__ inline bf16x4 to_bf4(float a, float b, float c, float d) {
  bf16x4 t; t[0] = (__bf16)a; t[1] = (__bf16)b; t[2] = (__bf16)c; t[3] = (__bf16)d; return t;
}

__device__ inline void gload16(const __bf16* g, __bf16* l) {
  __builtin_amdgcn_global_load_lds(
      (const __attribute__((address_space(1))) void*)g,
      (__attribute__((address_space(3))) void*)l, 16, 0, 0);
}

// ---------------------------------------------------------------------------
// Embedding gather
// ---------------------------------------------------------------------------
__global__ __launch_bounds__(256) void embed_kernel(const int* __restrict__ idx,
                                                    const float* __restrict__ W,
                                                    float* __restrict__ x) {
  int t = blockIdx.x;
  int v = idx[t];
  float4 val = *(const float4*)&W[(size_t)v * D_MODEL + threadIdx.x * 4];
  *(float4*)&x[(size_t)t * D_MODEL + threadIdx.x * 4] = val;
}

// ---------------------------------------------------------------------------
// RMSNorm: f32 in -> bf16 out
// ---------------------------------------------------------------------------
__global__ __launch_bounds__(256) void rmsnorm_kernel(const float* __restrict__ x,
                                                      const float* __restrict__ w,
                                                      __bf16* __restrict__ out) {
  int row = blockIdx.x;
  int tid = threadIdx.x;
  float4 v = *(const float4*)&x[(size_t)row * D_MODEL + tid * 4];
  float s = v.x * v.x + v.y * v.y + v.z * v.z + v.w * v.w;
#pragma unroll
  for (int m = 32; m >= 1; m >>= 1) s += __shfl_xor(s, m, 64);
  __shared__ float red[4];
  if ((tid & 63) == 0) red[tid >> 6] = s;
  __syncthreads();
  float tot = red[0] + red[1] + red[2] + red[3];
  float inv = rsqrtf(tot * (1.0f / (float)D_MODEL) + 1e-6f);
  float4 wv = *(const float4*)&w[tid * 4];
  bf16x4 o4 = to_bf4(v.x * inv * wv.x, v.y * inv * wv.y, v.z * inv * wv.z, v.w * inv * wv.w);
  *(bf16x4*)&out[(size_t)row * D_MODEL + tid * 4] = o4;
}

// ---------------------------------------------------------------------------
// RoPE cos/sin table
// ---------------------------------------------------------------------------
__global__ __launch_bounds__(256) void rope_table_kernel(float* __restrict__ tab) {
  int p = blockIdx.x * 256 + threadIdx.x;
  int t = p >> 5, i = p & 31;
  float freq = exp2f(-(float)i * (13.287712379549449f / 32.0f));
  float sn, cs;
  sincosf((float)t * freq, &sn, &cs);
  tab[p] = cs;
  tab[32768 + p] = sn;
}

// ---------------------------------------------------------------------------
// Merged per-layer weight transpose+convert (5 weights, one launch).
// ---------------------------------------------------------------------------
__global__ __launch_bounds__(256) void tp5_kernel(
    const float* __restrict__ Wqkv, const float* __restrict__ Wout,
    const float* __restrict__ Wg, const float* __restrict__ Wu,
    const float* __restrict__ Wd,
    __bf16* __restrict__ wqkvT, __bf16* __restrict__ woutT,
    __bf16* __restrict__ wguT, __bf16* __restrict__ wdT) {
  __shared__ __bf16 tile[64][65];
  int t = blockIdx.x;
  const float* in;
  __bf16* out;
  int R, C, Ro, rmul, roff, tr;
  if (t < 768)        { in = Wqkv; out = wqkvT; R = 1024; C = 3072; Ro = 1024; rmul = 1; roff = 0; tr = 16; }
  else if (t < 1024)  { t -= 768;  in = Wout; out = woutT; R = 1024; C = 1024; Ro = 1024; rmul = 1; roff = 0; tr = 16; }
  else if (t < 1728)  { t -= 1024; in = Wg; out = wguT; R = 1024; C = HID; Ro = 1024; rmul = 2; roff = 0; tr = 16; }
  else if (t < 2432)  { t -= 1728; in = Wu; out = wguT; R = 1024; C = HID; Ro = 1024; rmul = 2; roff = 1; tr = 16; }
  else                { t -= 2432; in = Wd; out = wdT; R = HID; C = 1024; Ro = HID_PAD; rmul = 1; roff = 0; tr = 44; }
  int r0 = (t % tr) * 64, c0 = (t / tr) * 64;
  int tid = threadIdx.x;
  bool fullc = (c0 + 64 <= C);
#pragma unroll
  for (int i = 0; i < 4; ++i) {
    int ri = i * 16 + (tid >> 4);
    int ci = (tid & 15) * 4;
    int r = r0 + ri;
    float4 v = {0.f, 0.f, 0.f, 0.f};
    if (r < R) {
      const float* p = in + (size_t)r * C + c0 + ci;
      if (fullc) {
        v = *(const float4*)p;
      } else {
        int c = c0 + ci;
        if (c + 0 < C) v.x = p[0];
        if (c + 1 < C) v.y = p[1];
        if (c + 2 < C) v.z = p[2];
        if (c + 3 < C) v.w = p[3];
      }
    }
    tile[ri][ci + 0] = (__bf16)v.x;
    tile[ri][ci + 1] = (__bf16)v.y;
    tile[ri][ci + 2] = (__bf16)v.z;
    tile[ri][ci + 3] = (__bf16)v.w;
  }
  __syncthreads();
#pragma unroll
  for (int i = 0; i < 4; ++i) {
    int oc = i * 16 + (tid >> 4);
    int orr = (tid & 15) * 4;
    bf16x4 tv;
    tv[0] = tile[orr + 0][oc];
    tv[1] = tile[orr + 1][oc];
    tv[2] = tile[orr + 2][oc];
    tv[3] = tile[orr + 3][oc];
    *(bf16x4*)&out[((size_t)(c0 + oc) * rmul + roff) * Ro + r0 + orr] = tv;
  }
}

// ---------------------------------------------------------------------------
// Plain f32 -> bf16 convert (W_emb)
// ---------------------------------------------------------------------------
__global__ __launch_bounds__(256) void convert_bf16_kernel(const float* __restrict__ in,
                                                           __bf16* __restrict__ out, int n4) {
  for (int i = blockIdx.x * 256 + threadIdx.x; i < n4; i += gridDim.x * 256) {
    float4 v = ((const float4*)in)[i];
    ((bf16x4*)out)[i] = to_bf4(v.x, v.y, v.z, v.w);
  }
}

// ---------------------------------------------------------------------------
// Deep-pipelined GEMM: C[M,N] = A[M,K] @ B^T, sigma-permuted LDS chunks,
// counted vmcnt, setprio. MF==8: fine m201-style sub-phase schedule with
// vmcnt+barrier BEFORE any ds_read of the tile (round-5 race fixed).
// Other MF: coarse loop (round-4-proven).
// EPI: 0 f32, 1 f32+residual, 2 bf16 silu(Cin)*acc, 3 bf16 plain,
//      4 interleaved-g/u fused silu (bf16, cols halved).
// ---------------------------------------------------------------------------
template <int BM, int BN, int WM, int WN, int EPI>
__global__ __launch_bounds__(WM * WN * 64, 2) void gemm8(
    const __bf16* __restrict__ A, const __bf16* __restrict__ B,
    const float* __restrict__ Cin, void* __restrict__ Cout,
    int K, int ldc) {
  constexpr int NTH = WM * WN * 64;
  constexpr int MF = BM / (16 * WM);
  constexpr int MG = (MF + 3) / 4;
  constexpr int CL = (MF < 4) ? MF : 4;
  constexpr int LA = (BM * 4) / NTH;
  constexpr int LB = (BN * 4) / NTH;
  static_assert(BN / WN == 64, "NF must be 4");
  __shared__ __align__(16) __bf16 lds[(BM + BN) * 128];

  const int tid = threadIdx.x;
  const int lane = tid & 63, wid = tid >> 6;
  const int wr = wid / WN, wn = wid % WN;
  const int lr = lane & 15, lg = lane >> 4;

  const int gx = gridDim.x;
  const int nwg = gx * gridDim.y;
  const int orig = blockIdx.y * gx + blockIdx.x;
  const int q = nwg >> 3, r8 = nwg & 7;
  const int xcd = orig & 7, loc = orig >> 3;
  const int swz = ((xcd < r8) ? xcd * (q + 1) : r8 * (q + 1) + (xcd - r8) * q) + loc;
  const int brow = (swz % gx) * BM;
  const int bcol = (swz / gx) * BN;

  const __bf16* pAg[LA];
  const __bf16* pBg[LB];
  int opA[LA], opB[LB];
#pragma unroll
  for (int i = 0; i < LA; ++i) {
    int p = tid + i * NTH;
    int row = ((p >> 6) << 4) | (p & 15), j = (p >> 4) & 3;
    pAg[i] = A + (size_t)(brow + row) * K + j * 8;
    opA[i] = p * 8;
  }
#pragma unroll
  for (int i = 0; i < LB; ++i) {
    int p = tid + i * NTH;
    int row = ((p >> 6) << 4) | (p & 15), j = (p >> 4) & 3;
    pBg[i] = B + (size_t)(bcol + row) * K + j * 8;
    opB[i] = p * 8;
  }

  const int ntiles = K >> 6;

  auto STAGE_A = [&](int v, int kkq) {
    int vs = v < ntiles ? v : ntiles - 1;
    int ko = vs * 64 + kkq * 32;
    int sa = (v & 1) * (BM * 64) + kkq * (BM * 32);
#pragma unroll
    for (int i = 0; i < LA; ++i) gload16(pAg[i] + ko, lds + sa + opA[i]);
  };
  auto STAGE_B = [&](int v, int kkq) {
    int vs = v < ntiles ? v : ntiles - 1;
    int ko = vs * 64 + kkq * 32;
    int sb = BM * 128 + (v & 1) * (BN * 64) + kkq * (BN * 32);
#pragma unroll
    for (int i = 0; i < LB; ++i) gload16(pBg[i] + ko, lds + sb + opB[i]);
  };

  f32x4 acc[MF][4];
#pragma unroll
  for (int m = 0; m < MF; ++m)
#pragma unroll
    for (int n = 0; n < 4; ++n) acc[m][n] = (f32x4){0.f, 0.f, 0.f, 0.f};

  STAGE_A(0, 0); STAGE_B(0, 0);
  STAGE_A(0, 1); STAGE_B(0, 1);
  STAGE_A(1, 0); STAGE_B(1, 0);

  const int fragoff = lg * 128 + lr * 8;

  if constexpr (MF == 8) {
    // ---- fine schedule: vmcnt+barrier FIRST, then 2 sub-phases per kk ----
    for (int u = 0; u < ntiles; ++u) {
      const int buf = u & 1;
#pragma unroll
      for (int kk = 0; kk < 2; ++kk) {
        const int v = (kk == 0) ? u + 1 : u + 2;
        const int kkq = kk ^ 1;
        const __bf16* Ab = lds + buf * (BM * 64) + kk * (BM * 32);
        const __bf16* Bb = lds + BM * 128 + buf * (BN * 64) + kk * (BN * 32);
        // tile (u,kk) data arrival + overwrite-slot free
        asm volatile("s_waitcnt vmcnt(8)" ::: "memory");
        __builtin_amdgcn_sched_barrier(0);
        __builtin_amdgcn_s_barrier();
        __builtin_amdgcn_sched_barrier(0);
        // sub-phase 0: stage A-part, read B(all)+A(low), 16 MFMA
        STAGE_A(v, kkq);
        bf16x8 bfr[4], af0[4];
#pragma unroll
        for (int n = 0; n < 4; ++n)
          bfr[n] = *(const bf16x8*)(Bb + (wn * 64 + n * 16) * 32 + fragoff);
#pragma unroll
        for (int i = 0; i < 4; ++i)
          af0[i] = *(const bf16x8*)(Ab + (wr * 128 + i * 16) * 32 + fragoff);
        asm volatile("s_waitcnt lgkmcnt(0)" ::: "memory");
        __builtin_amdgcn_sched_barrier(0);
        __builtin_amdgcn_s_setprio(1);
#pragma unroll
        for (int i = 0; i < 4; ++i)
#pragma unroll
          for (int n = 0; n < 4; ++n)
            acc[i][n] = __builtin_amdgcn_mfma_f32_16x16x32_bf16(af0[i], bfr[n], acc[i][n], 0, 0, 0);
        __builtin_amdgcn_s_setprio(0);
        __builtin_amdgcn_s_barrier();
        // sub-phase 1: stage B-part, read A(high), 16 MFMA
        STAGE_B(v, kkq);
        bf16x8 af1[4];
#pragma unroll
        for (int i = 0; i < 4; ++i)
          af1[i] = *(const bf16x8*)(Ab + (wr * 128 + 64 + i * 16) * 32 + fragoff);
        asm volatile("s_waitcnt lgkmcnt(0)" ::: "memory");
        __builtin_amdgcn_sched_barrier(0);
        __builtin_amdgcn_s_setprio(1);
#pragma unroll
        for (int i = 0; i < 4; ++i)
#pragma unroll
          for (int n = 0; n < 4; ++n)
            acc[4 + i][n] = __builtin_amdgcn_mfma_f32_16x16x32_bf16(af1[i], bfr[n], acc[4 + i][n], 0, 0, 0);
        __builtin_amdgcn_s_setprio(0);
        __builtin_amdgcn_s_barrier();
      }
    }
  } else {
    // ---- coarse schedule (round-4-proven) ----
    for (int u = 0; u < ntiles; ++u) {
      const int buf = u & 1;
#pragma unroll
      for (int kk = 0; kk < 2; ++kk) {
        if constexpr (LA + LB == 3) asm volatile("s_waitcnt vmcnt(6)" ::: "memory");
        else                        asm volatile("s_waitcnt vmcnt(8)" ::: "memory");
        __builtin_amdgcn_sched_barrier(0);
        __builtin_amdgcn_s_barrier();
        __builtin_amdgcn_sched_barrier(0);
        const int v = (kk == 0) ? u + 1 : u + 2;
        const int kkq = kk ^ 1;
        STAGE_A(v, kkq);
        STAGE_B(v, kkq);
        const __bf16* Ab = lds + buf * (BM * 64) + kk * (BM * 32);
        const __bf16* Bb = lds + BM * 128 + buf * (BN * 64) + kk * (BN * 32);
        bf16x8 bfr[4];
#pragma unroll
        for (int n = 0; n < 4; ++n)
          bfr[n] = *(const bf16x8*)(Bb + (wn * 64 + n * 16) * 32 + fragoff);
#pragma unroll
        for (int mg = 0; mg < MG; ++mg) {
          bf16x8 afr[CL];
#pragma unroll
          for (int i = 0; i < CL; ++i)
            afr[i] = *(const bf16x8*)(Ab + (wr * (BM / WM) + (mg * 4 + i) * 16) * 32 + fragoff);
          __builtin_amdgcn_s_setprio(1);
#pragma unroll
          for (int i = 0; i < CL; ++i)
#pragma unroll
            for (int n = 0; n < 4; ++n)
              acc[mg * 4 + i][n] =
                  __builtin_amdgcn_mfma_f32_16x16x32_bf16(afr[i], bfr[n], acc[mg * 4 + i][n], 0, 0, 0);
          __builtin_amdgcn_s_setprio(0);
        }
      }
    }
  }

#pragma unroll
  for (int m = 0; m < MF; ++m) {
#pragma unroll
    for (int n = 0; n < 4; ++n) {
#pragma unroll
      for (int rr = 0; rr < 4; ++rr) {
        int row = brow + wr * (BM / WM) + m * 16 + lg * 4 + rr;
        int col = bcol + wn * 64 + n * 16 + lr;
        size_t off = (size_t)row * ldc + col;
        float vv = acc[m][n][rr];
        if (EPI == 0) {
          ((float*)Cout)[off] = vv;
        } else if (EPI == 1) {
          ((float*)Cout)[off] = Cin[off] + vv;
        } else if (EPI == 2) {
          float gv = Cin[off];
          ((__bf16*)Cout)[off] = (__bf16)(gv / (1.f + __expf(-gv)) * vv);
        } else if (EPI == 3) {
          ((__bf16*)Cout)[off] = (__bf16)vv;
        } else {
          float uv = __shfl_xor(vv, 1);
          if ((lr & 1) == 0) {
            float r = vv / (1.f + __expf(-vv)) * uv;
            ((__bf16*)Cout)[(size_t)row * ldc + (col >> 1)] = (__bf16)r;
          }
        }
      }
    }
  }
}

// ---------------------------------------------------------------------------
// Rope helper (8-wide pair chunk)
// ---------------------------------------------------------------------------
__device__ inline void rope_chunk(const __bf16* p, const float* __restrict__ tab,
                                  int t, int d0, bf16x8& olo, bf16x8& ohi) {
  bf16x8 a8 = *(const bf16x8*)p;
  bf16x8 b8 = *(const bf16x8*)(p + 32);
  const float* ct = tab + t * 32 + d0;
  const float* st = tab + 32768 + t * 32 + d0;
  float4 c0 = *(const float4*)ct, c1 = *(const float4*)(ct + 4);
  float4 s0 = *(const float4*)st, s1 = *(const float4*)(st + 4);
  float cs[8] = {c0.x, c0.y, c0.z, c0.w, c1.x, c1.y, c1.z, c1.w};
  float ss[8] = {s0.x, s0.y, s0.z, s0.w, s1.x, s1.y, s1.z, s1.w};
#pragma unroll
  for (int j = 0; j < 8; ++j) {
    float av = (float)a8[j], bv = (float)b8[j];
    olo[j] = (__bf16)(av * cs[j] - bv * ss[j]);
    ohi[j] = (__bf16)(av * ss[j] + bv * cs[j]);
  }
}

// ---------------------------------------------------------------------------
// prep: rope(q)->Qr, rope(k)->Kr, v^T -> Vt. Qr/Kr: [bh][t][64]; Vt: [bh][64][1024].
// ---------------------------------------------------------------------------
__global__ __launch_bounds__(256) void prep_kernel(const __bf16* __restrict__ qkv,
                                                   const float* __restrict__ tab,
                                                   __bf16* __restrict__ Qr,
                                                   __bf16* __restrict__ Kr,
                                                   __bf16* __restrict__ Vt) {
  __shared__ __bf16 lsV[64][72];
  const int tid = threadIdx.x;
  const int bh = blockIdx.y, b = bh >> 4, h = bh & 15;
  const int t0 = blockIdx.x * 64;
  const size_t qbase = (size_t)b * T_SEQ * 3072 + h * 64;

  int row = tid >> 2, pc = tid & 3;
  int t = t0 + row;
  int tl = t & 1023;
  {
    int d0 = pc * 8;
    bf16x8 olo, ohi;
    rope_chunk(qkv + qbase + (size_t)t * 3072 + d0, tab, tl, d0, olo, ohi);
    __bf16* qo = Qr + ((size_t)bh * T_SEQ + t) * 64;
    *(bf16x8*)(qo + d0) = olo;
    *(bf16x8*)(qo + d0 + 32) = ohi;
    rope_chunk(qkv + qbase + (size_t)t * 3072 + 1024 + d0, tab, tl, d0, olo, ohi);
    __bf16* ko = Kr + ((size_t)bh * T_SEQ + t) * 64;
    *(bf16x8*)(ko + d0) = olo;
    *(bf16x8*)(ko + d0 + 32) = ohi;
  }
  {
    int c = pc * 16;
    bf16x8 v0 = *(const bf16x8*)(qkv + qbase + (size_t)t * 3072 + 2048 + c);
    bf16x8 v1 = *(const bf16x8*)(qkv + qbase + (size_t)t * 3072 + 2048 + c + 8);
    *(bf16x8*)&lsV[row][c] = v0;
    *(bf16x8*)&lsV[row][c + 8] = v1;
  }
  __syncthreads();
  {
    int d = tid >> 2, tc = (tid & 3) * 16;
    bf16x8 o0, o1;
#pragma unroll
    for (int j = 0; j < 8; ++j) o0[j] = lsV[tc + j][d];
#pragma unroll
    for (int j = 0; j < 8; ++j) o1[j] = lsV[tc + 8 + j][d];
    __bf16* vo = Vt + ((size_t)bh * 64 + d) * T_SEQ + t0 + tc;
    *(bf16x8*)vo = o0;
    *(bf16x8*)(vo + 8) = o1;
  }
}

// ---------------------------------------------------------------------------
// Flash attention: Q/K/Vt staged via global_load_lds into sigma layout.
// Block = 64 q-rows x one (b,h), 4 waves x 16 q-rows, KVBLK=128.
// ---------------------------------------------------------------------------
__global__ __launch_bounds__(256) void attn_kernel(const __bf16* __restrict__ Qr,
                                                   const __bf16* __restrict__ Kr,
                                                   const __bf16* __restrict__ Vt,
                                                   __bf16* __restrict__ o) {
  __shared__ __align__(16) __bf16 lds[28672];
  const int tid = threadIdx.x;
  const int lane = tid & 63, w = tid >> 6;
  const int lr = lane & 15, lg = lane >> 4;
  const int bh = blockIdx.y, b = bh >> 4, h = bh & 15;
  const int qb = blockIdx.x, q0 = qb * 64;
  const __bf16* Qg = Qr + ((size_t)bh * T_SEQ + q0) * 64;
  const __bf16* Kg = Kr + (size_t)bh * T_SEQ * 64;
  const __bf16* Vg = Vt + (size_t)bh * 64 * T_SEQ;
  const float scale = 0.125f;

  {
    int row = ((tid >> 6) << 4) | (tid & 15);
    int j = (tid >> 4) & 3;
    gload16(Qg + row * 64 + j * 8, lds + tid * 8);
    gload16(Qg + row * 64 + 32 + j * 8, lds + 2048 + tid * 8);
  }

  f32x4 accO[4];
#pragma unroll
  for (int n = 0; n < 4; ++n) accO[n] = (f32x4){0.f, 0.f, 0.f, 0.f};
  float mrow[4], lrow[4];
#pragma unroll
  for (int r = 0; r < 4; ++r) { mrow[r] = -1e30f; lrow[r] = 0.f; }

  const int ntile = ((q0 + 63) >> 7) + 1;
  __bf16* Pw = lds + 20480 + w * 2048;

  for (int tt = 0; tt < ntile; ++tt) {
    const int j0 = tt * 128;
    __syncthreads();
#pragma unroll
    for (int i = 0; i < 2; ++i) {
      int p = tid + i * 256;
      int row = ((p >> 6) << 4) | (p & 15), j = (p >> 4) & 3;
      const __bf16* src = Kg + (size_t)(j0 + row) * 64 + j * 8;
      gload16(src, lds + 4096 + p * 8);
      gload16(src + 32, lds + 8192 + p * 8);
    }
#pragma unroll
    for (int s = 0; s < 4; ++s) {
      int d = ((tid >> 6) << 4) | (tid & 15), j = (tid >> 4) & 3;
      gload16(Vg + (size_t)d * T_SEQ + j0 + s * 32 + j * 8, lds + 12288 + s * 2048 + tid * 8);
    }
    __syncthreads();

    f32x4 s4[8];
#pragma unroll
    for (int n = 0; n < 8; ++n) s4[n] = (f32x4){0.f, 0.f, 0.f, 0.f};
#pragma unroll
    for (int kk = 0; kk < 2; ++kk) {
      bf16x8 aq = *(const bf16x8*)(lds + kk * 2048 + (w * 64 + lg * 16 + lr) * 8);
      __builtin_amdgcn_s_setprio(1);
#pragma unroll
      for (int jf = 0; jf < 8; ++jf) {
        bf16x8 bk = *(const bf16x8*)(lds + 4096 + kk * 4096 + (jf * 64 + lg * 16 + lr) * 8);
        s4[jf] = __builtin_amdgcn_mfma_f32_16x16x32_bf16(aq, bk, s4[jf], 0, 0, 0);
      }
      __builtin_amdgcn_s_setprio(0);
    }

    float pm[4];
#pragma unroll
    for (int r = 0; r < 4; ++r) pm[r] = -1e30f;
#pragma unroll
    for (int jf = 0; jf < 8; ++jf) {
      int gj = j0 + jf * 16 + lr;
#pragma unroll
      for (int r = 0; r < 4; ++r) {
        int gq = q0 + w * 16 + lg * 4 + r;
        float sv = s4[jf][r] * scale;
        if (gj > gq) sv = -1e30f;
        s4[jf][r] = sv;
        pm[r] = fmaxf(pm[r], sv);
      }
    }
#pragma unroll
    for (int r = 0; r < 4; ++r) {
#pragma unroll
      for (int m = 8; m >= 1; m >>= 1) pm[r] = fmaxf(pm[r], __shfl_xor(pm[r], m, 64));
    }
    float alpha[4];
#pragma unroll
    for (int r = 0; r < 4; ++r) {
      float mn = fmaxf(mrow[r], pm[r]);
      alpha[r] = expf(mrow[r] - mn);
      mrow[r] = mn;
    }
    float ps[4] = {0.f, 0.f, 0.f, 0.f};
#pragma unroll
    for (int jf = 0; jf < 8; ++jf) {
#pragma unroll
      for (int r = 0; r < 4; ++r) {
        float p = expf(s4[jf][r] - mrow[r]);
        s4[jf][r] = p;
        ps[r] += p;
      }
    }
#pragma unroll
    for (int r = 0; r < 4; ++r) {
#pragma unroll
      for (int m = 8; m >= 1; m >>= 1) ps[r] += __shfl_xor(ps[r], m, 64);
      lrow[r] = lrow[r] * alpha[r] + ps[r];
    }
#pragma unroll
    for (int n = 0; n < 4; ++n) {
#pragma unroll
      for (int r = 0; r < 4; ++r) accO[n][r] *= alpha[r];
    }

#pragma unroll
    for (int jf = 0; jf < 8; ++jf) {
      int s = jf >> 1;
      int rem = ((jf & 1) << 4) + lr;
      int base = s * 512 + (rem >> 3) * 128 + (rem & 7);
#pragma unroll
      for (int r = 0; r < 4; ++r) {
        int qloc = lg * 4 + r;
        Pw[base + qloc * 8] = (__bf16)s4[jf][r];
      }
    }
    asm volatile("s_waitcnt lgkmcnt(0)" ::: "memory");
    __builtin_amdgcn_sched_barrier(0);

#pragma unroll
    for (int s = 0; s < 4; ++s) {
      bf16x8 pa = *(const bf16x8*)(Pw + s * 512 + (lg * 16 + lr) * 8);
      __builtin_amdgcn_s_setprio(1);
#pragma unroll
      for (int nd = 0; nd < 4; ++nd) {
        bf16x8 bv = *(const bf16x8*)(lds + 12288 + s * 2048 + (nd * 64 + lg * 16 + lr) * 8);
        accO[nd] = __builtin_amdgcn_mfma_f32_16x16x32_bf16(pa, bv, accO[nd], 0, 0, 0);
      }
      __builtin_amdgcn_s_setprio(0);
    }
  }

#pragma unroll
  for (int nd = 0; nd < 4; ++nd) {
#pragma unroll
    for (int r = 0; r < 4; ++r) {
      int gq = q0 + w * 16 + lg * 4 + r;
      float val = accO[nd][r] / lrow[r];
      o[(size_t)(b * T_SEQ + gq) * D_MODEL + h * 64 + nd * 16 + lr] = (__bf16)val;
    }
  }
}

// ---------------------------------------------------------------------------
extern "C" void kernel_launch(void* const* d_in, const int* in_sizes, int n_in,
                              void* d_out, int out_size, void* d_ws, size_t ws_size,
                              hipStream_t stream) {
  const int*   idx     = (const int*)d_in[0];
  const float* W_emb   = (const float*)d_in[1];
  const float* norm1_w = (const float*)d_in[2];
  const float* Wqkv    = (const float*)d_in[3];
  const float* Wout    = (const float*)d_in[4];
  const float* norm2_w = (const float*)d_in[5];
  const float* Wg      = (const float*)d_in[6];
  const float* Wu      = (const float*)d_in[7];
  const float* Wd      = (const float*)d_in[8];
  const float* fnorm   = (const float*)d_in[9];
  float* out = (float*)d_out;

  float*  x    = (float*)d_ws;                              // 2048*1024 f32
  float*  tab  = x + (size_t)NTOK * D_MODEL;                // 2*32768 f32
  __bf16* qkvb = (__bf16*)(tab + 2 * 32768);                // 2048*3072
  __bf16* hb   = qkvb + (size_t)NTOK * 3 * D_MODEL;         // 2048*1024
  __bf16* ob   = hb + (size_t)NTOK * D_MODEL;               // 2048*1024
  __bf16* ga   = ob + (size_t)NTOK * D_MODEL;               // 2048*2816
  __bf16* Qrb  = ga + (size_t)NTOK * HID_PAD;               // 32*1024*64
  __bf16* Krb  = Qrb + (size_t)32 * T_SEQ * 64;
  __bf16* Vtb  = Krb + (size_t)32 * T_SEQ * 64;
  __bf16* wbuf = Vtb + (size_t)32 * T_SEQ * 64;

  __bf16* wqkvT = wbuf;                                     // [3072][1024]
  __bf16* woutT = wqkvT + (size_t)3 * D_MODEL * D_MODEL;    // [1024][1024]
  __bf16* wguT  = woutT + (size_t)D_MODEL * D_MODEL;        // [5632][1024]
  __bf16* wdT   = wguT + (size_t)2 * HID_PAD * D_MODEL;     // [1024][2816]

  embed_kernel<<<NTOK, 256, 0, stream>>>(idx, W_emb, x);
  rope_table_kernel<<<128, 256, 0, stream>>>(tab);

  for (int l = 0; l < NLAYER; ++l) {
    tp5_kernel<<<3136, 256, 0, stream>>>(
        Wqkv + (size_t)l * D_MODEL * 3 * D_MODEL,
        Wout + (size_t)l * D_MODEL * D_MODEL,
        Wg + (size_t)l * D_MODEL * HID,
        Wu + (size_t)l * D_MODEL * HID,
        Wd + (size_t)l * HID * D_MODEL,
        wqkvT, woutT, wguT, wdT);

    rmsnorm_kernel<<<NTOK, 256, 0, stream>>>(x, norm1_w + (size_t)l * D_MODEL, hb);
    gemm8<128, 256, 2, 4, 3><<<dim3(16, 12), 512, 0, stream>>>(
        hb, wqkvT, nullptr, qkvb, D_MODEL, 3 * D_MODEL);
    prep_kernel<<<dim3(16, 32), 256, 0, stream>>>(qkvb, tab, Qrb, Krb, Vtb);
    attn_kernel<<<dim3(16, 32), 256, 0, stream>>>(Qrb, Krb, Vtb, ob);
    gemm8<128, 64, 4, 1, 1><<<dim3(16, 16), 256, 0, stream>>>(
        ob, woutT, x, x, D_MODEL, D_MODEL);
    rmsnorm_kernel<<<NTOK, 256, 0, stream>>>(x, norm2_w + (size_t)l * D_MODEL, hb);
    gemm8<256, 256, 2, 4, 4><<<dim3(8, 22), 512, 0, stream>>>(
        hb, wguT, nullptr, ga, D_MODEL, HID_PAD);
    gemm8<128, 64, 4, 1, 1><<<dim3(16, 16), 256, 0, stream>>>(
        ga, wdT, x, x, HID_PAD, D_MODEL);
  }

  rmsnorm_kernel<<<NTOK, 256, 0, stream>>>(x, fnorm, hb);
  convert_bf16_kernel<<<2048, 256, 0, stream>>>(W_emb, wbuf, VOCAB * D_MODEL / 4);
  gemm8<256, 256, 2, 4, 0><<<dim3(8, 125), 512, 0, stream>>>(
      hb, wbuf, nullptr, out, D_MODEL, VOCAB);
}

// Round 7
// 1733.756 us; speedup vs baseline: 4.8313x; 1.0265x over previous
//
#include <hip/hip_runtime.h>
#include <cstdint>
#include <cmath>

#define D_MODEL 1024
#define T_SEQ   1024
#define NHEAD   16
#define NLAYER  8
#define HID     2734
#define HID_PAD 2816
#define NTOK    2048
#define VOCAB   32000

typedef __bf16 bf16x8 __attribute__((ext_vector_type(8)));
typedef __bf16 bf16x4 __attribute__((ext_vector_type(4)));
typedef float  f32x4  __attribute__((ext_vector_type(4)));

__device__ inline bf16x4 to_bf4(float a, float b, float c, float d) {
  bf16x4 t; t[0] = (__bf16)a; t[1] = (__bf16)b; t[2] = (__bf16)c; t[3] = (__bf16)d; return t;
}

__device__ inline void gload16(const __bf16* g, __bf16* l) {
  __builtin_amdgcn_global_load_lds(
      (const __attribute__((address_space(1))) void*)g,
      (__attribute__((address_space(3))) void*)l, 16, 0, 0);
}

// ---------------------------------------------------------------------------
// Embedding gather
// ---------------------------------------------------------------------------
__global__ __launch_bounds__(256) void embed_kernel(const int* __restrict__ idx,
                                                    const float* __restrict__ W,
                                                    float* __restrict__ x) {
  int t = blockIdx.x;
  int v = idx[t];
  float4 val = *(const float4*)&W[(size_t)v * D_MODEL + threadIdx.x * 4];
  *(float4*)&x[(size_t)t * D_MODEL + threadIdx.x * 4] = val;
}

// ---------------------------------------------------------------------------
// RMSNorm: f32 in -> bf16 out
// ---------------------------------------------------------------------------
__global__ __launch_bounds__(256) void rmsnorm_kernel(const float* __restrict__ x,
                                                      const float* __restrict__ w,
                                                      __bf16* __restrict__ out) {
  int row = blockIdx.x;
  int tid = threadIdx.x;
  float4 v = *(const float4*)&x[(size_t)row * D_MODEL + tid * 4];
  float s = v.x * v.x + v.y * v.y + v.z * v.z + v.w * v.w;
#pragma unroll
  for (int m = 32; m >= 1; m >>= 1) s += __shfl_xor(s, m, 64);
  __shared__ float red[4];
  if ((tid & 63) == 0) red[tid >> 6] = s;
  __syncthreads();
  float tot = red[0] + red[1] + red[2] + red[3];
  float inv = rsqrtf(tot * (1.0f / (float)D_MODEL) + 1e-6f);
  float4 wv = *(const float4*)&w[tid * 4];
  bf16x4 o4 = to_bf4(v.x * inv * wv.x, v.y * inv * wv.y, v.z * inv * wv.z, v.w * inv * wv.w);
  *(bf16x4*)&out[(size_t)row * D_MODEL + tid * 4] = o4;
}

// ---------------------------------------------------------------------------
// RoPE cos/sin table
// ---------------------------------------------------------------------------
__global__ __launch_bounds__(256) void rope_table_kernel(float* __restrict__ tab) {
  int p = blockIdx.x * 256 + threadIdx.x;
  int t = p >> 5, i = p & 31;
  float freq = exp2f(-(float)i * (13.287712379549449f / 32.0f));
  float sn, cs;
  sincosf((float)t * freq, &sn, &cs);
  tab[p] = cs;
  tab[32768 + p] = sn;
}

// ---------------------------------------------------------------------------
// Merged per-layer weight transpose+convert (5 weights, one launch).
// ---------------------------------------------------------------------------
__global__ __launch_bounds__(256) void tp5_kernel(
    const float* __restrict__ Wqkv, const float* __restrict__ Wout,
    const float* __restrict__ Wg, const float* __restrict__ Wu,
    const float* __restrict__ Wd,
    __bf16* __restrict__ wqkvT, __bf16* __restrict__ woutT,
    __bf16* __restrict__ wguT, __bf16* __restrict__ wdT) {
  __shared__ __bf16 tile[64][65];
  int t = blockIdx.x;
  const float* in;
  __bf16* out;
  int R, C, Ro, rmul, roff, tr;
  if (t < 768)        { in = Wqkv; out = wqkvT; R = 1024; C = 3072; Ro = 1024; rmul = 1; roff = 0; tr = 16; }
  else if (t < 1024)  { t -= 768;  in = Wout; out = woutT; R = 1024; C = 1024; Ro = 1024; rmul = 1; roff = 0; tr = 16; }
  else if (t < 1728)  { t -= 1024; in = Wg; out = wguT; R = 1024; C = HID; Ro = 1024; rmul = 2; roff = 0; tr = 16; }
  else if (t < 2432)  { t -= 1728; in = Wu; out = wguT; R = 1024; C = HID; Ro = 1024; rmul = 2; roff = 1; tr = 16; }
  else                { t -= 2432; in = Wd; out = wdT; R = HID; C = 1024; Ro = HID_PAD; rmul = 1; roff = 0; tr = 44; }
  int r0 = (t % tr) * 64, c0 = (t / tr) * 64;
  int tid = threadIdx.x;
  bool fullc = (c0 + 64 <= C);
#pragma unroll
  for (int i = 0; i < 4; ++i) {
    int ri = i * 16 + (tid >> 4);
    int ci = (tid & 15) * 4;
    int r = r0 + ri;
    float4 v = {0.f, 0.f, 0.f, 0.f};
    if (r < R) {
      const float* p = in + (size_t)r * C + c0 + ci;
      if (fullc) {
        v = *(const float4*)p;
      } else {
        int c = c0 + ci;
        if (c + 0 < C) v.x = p[0];
        if (c + 1 < C) v.y = p[1];
        if (c + 2 < C) v.z = p[2];
        if (c + 3 < C) v.w = p[3];
      }
    }
    tile[ri][ci + 0] = (__bf16)v.x;
    tile[ri][ci + 1] = (__bf16)v.y;
    tile[ri][ci + 2] = (__bf16)v.z;
    tile[ri][ci + 3] = (__bf16)v.w;
  }
  __syncthreads();
#pragma unroll
  for (int i = 0; i < 4; ++i) {
    int oc = i * 16 + (tid >> 4);
    int orr = (tid & 15) * 4;
    bf16x4 tv;
    tv[0] = tile[orr + 0][oc];
    tv[1] = tile[orr + 1][oc];
    tv[2] = tile[orr + 2][oc];
    tv[3] = tile[orr + 3][oc];
    *(bf16x4*)&out[((size_t)(c0 + oc) * rmul + roff) * Ro + r0 + orr] = tv;
  }
}

// ---------------------------------------------------------------------------
// Plain f32 -> bf16 convert (W_emb)
// ---------------------------------------------------------------------------
__global__ __launch_bounds__(256) void convert_bf16_kernel(const float* __restrict__ in,
                                                           __bf16* __restrict__ out, int n4) {
  for (int i = blockIdx.x * 256 + threadIdx.x; i < n4; i += gridDim.x * 256) {
    float4 v = ((const float4*)in)[i];
    ((bf16x4*)out)[i] = to_bf4(v.x, v.y, v.z, v.w);
  }
}

// ---------------------------------------------------------------------------
// Deep-pipelined GEMM: C[M,N] = A[M,K] @ B^T, sigma-permuted LDS chunks,
// counted vmcnt, setprio.
// EPI: 0 f32, 1 f32+residual, 4 interleaved-g/u fused silu (bf16, cols halved),
//      5 fused qkv postprocess: rope(q)->Qr, rope(k)->Kr, v^T->Vt.
// ---------------------------------------------------------------------------
template <int BM, int BN, int WM, int WN, int EPI>
__global__ __launch_bounds__(WM * WN * 64, 2) void gemm8(
    const __bf16* __restrict__ A, const __bf16* __restrict__ B,
    const float* __restrict__ Cin, void* __restrict__ Cout,
    int K, int ldc,
    const float* __restrict__ Tab, __bf16* __restrict__ Qr,
    __bf16* __restrict__ Kr, __bf16* __restrict__ Vt) {
  constexpr int NTH = WM * WN * 64;
  constexpr int MF = BM / (16 * WM);
  constexpr int MG = (MF + 3) / 4;
  constexpr int CL = (MF < 4) ? MF : 4;
  constexpr int LA = (BM * 4) / NTH;
  constexpr int LB = (BN * 4) / NTH;
  static_assert(BN / WN == 64, "NF must be 4");
  __shared__ __align__(16) __bf16 lds[(BM + BN) * 128];

  const int tid = threadIdx.x;
  const int lane = tid & 63, wid = tid >> 6;
  const int wr = wid / WN, wn = wid % WN;
  const int lr = lane & 15, lg = lane >> 4;

  const int gx = gridDim.x;
  const int nwg = gx * gridDim.y;
  const int orig = blockIdx.y * gx + blockIdx.x;
  const int q = nwg >> 3, r8 = nwg & 7;
  const int xcd = orig & 7, loc = orig >> 3;
  const int swz = ((xcd < r8) ? xcd * (q + 1) : r8 * (q + 1) + (xcd - r8) * q) + loc;
  const int brow = (swz % gx) * BM;
  const int bcol = (swz / gx) * BN;

  const __bf16* pAg[LA];
  const __bf16* pBg[LB];
  int opA[LA], opB[LB];
#pragma unroll
  for (int i = 0; i < LA; ++i) {
    int p = tid + i * NTH;
    int row = ((p >> 6) << 4) | (p & 15), j = (p >> 4) & 3;
    pAg[i] = A + (size_t)(brow + row) * K + j * 8;
    opA[i] = p * 8;
  }
#pragma unroll
  for (int i = 0; i < LB; ++i) {
    int p = tid + i * NTH;
    int row = ((p >> 6) << 4) | (p & 15), j = (p >> 4) & 3;
    pBg[i] = B + (size_t)(bcol + row) * K + j * 8;
    opB[i] = p * 8;
  }

  const int ntiles = K >> 6;

  auto STAGE_A = [&](int v, int kkq) {
    int vs = v < ntiles ? v : ntiles - 1;
    int ko = vs * 64 + kkq * 32;
    int sa = (v & 1) * (BM * 64) + kkq * (BM * 32);
#pragma unroll
    for (int i = 0; i < LA; ++i) gload16(pAg[i] + ko, lds + sa + opA[i]);
  };
  auto STAGE_B = [&](int v, int kkq) {
    int vs = v < ntiles ? v : ntiles - 1;
    int ko = vs * 64 + kkq * 32;
    int sb = BM * 128 + (v & 1) * (BN * 64) + kkq * (BN * 32);
#pragma unroll
    for (int i = 0; i < LB; ++i) gload16(pBg[i] + ko, lds + sb + opB[i]);
  };

  f32x4 acc[MF][4];
#pragma unroll
  for (int m = 0; m < MF; ++m)
#pragma unroll
    for (int n = 0; n < 4; ++n) acc[m][n] = (f32x4){0.f, 0.f, 0.f, 0.f};

  STAGE_A(0, 0); STAGE_B(0, 0);
  STAGE_A(0, 1); STAGE_B(0, 1);
  STAGE_A(1, 0); STAGE_B(1, 0);

  const int fragoff = lg * 128 + lr * 8;

  if constexpr (MF == 8) {
    for (int u = 0; u < ntiles; ++u) {
      const int buf = u & 1;
#pragma unroll
      for (int kk = 0; kk < 2; ++kk) {
        const int v = (kk == 0) ? u + 1 : u + 2;
        const int kkq = kk ^ 1;
        const __bf16* Ab = lds + buf * (BM * 64) + kk * (BM * 32);
        const __bf16* Bb = lds + BM * 128 + buf * (BN * 64) + kk * (BN * 32);
        asm volatile("s_waitcnt vmcnt(8)" ::: "memory");
        __builtin_amdgcn_sched_barrier(0);
        __builtin_amdgcn_s_barrier();
        __builtin_amdgcn_sched_barrier(0);
        STAGE_A(v, kkq);
        bf16x8 bfr[4], af0[4];
#pragma unroll
        for (int n = 0; n < 4; ++n)
          bfr[n] = *(const bf16x8*)(Bb + (wn * 64 + n * 16) * 32 + fragoff);
#pragma unroll
        for (int i = 0; i < 4; ++i)
          af0[i] = *(const bf16x8*)(Ab + (wr * 128 + i * 16) * 32 + fragoff);
        asm volatile("s_waitcnt lgkmcnt(0)" ::: "memory");
        __builtin_amdgcn_sched_barrier(0);
        __builtin_amdgcn_s_setprio(1);
#pragma unroll
        for (int i = 0; i < 4; ++i)
#pragma unroll
          for (int n = 0; n < 4; ++n)
            acc[i][n] = __builtin_amdgcn_mfma_f32_16x16x32_bf16(af0[i], bfr[n], acc[i][n], 0, 0, 0);
        __builtin_amdgcn_s_setprio(0);
        __builtin_amdgcn_s_barrier();
        STAGE_B(v, kkq);
        bf16x8 af1[4];
#pragma unroll
        for (int i = 0; i < 4; ++i)
          af1[i] = *(const bf16x8*)(Ab + (wr * 128 + 64 + i * 16) * 32 + fragoff);
        asm volatile("s_waitcnt lgkmcnt(0)" ::: "memory");
        __builtin_amdgcn_sched_barrier(0);
        __builtin_amdgcn_s_setprio(1);
#pragma unroll
        for (int i = 0; i < 4; ++i)
#pragma unroll
          for (int n = 0; n < 4; ++n)
            acc[4 + i][n] = __builtin_amdgcn_mfma_f32_16x16x32_bf16(af1[i], bfr[n], acc[4 + i][n], 0, 0, 0);
        __builtin_amdgcn_s_setprio(0);
        __builtin_amdgcn_s_barrier();
      }
    }
  } else {
    for (int u = 0; u < ntiles; ++u) {
      const int buf = u & 1;
#pragma unroll
      for (int kk = 0; kk < 2; ++kk) {
        if constexpr (LA + LB == 3) asm volatile("s_waitcnt vmcnt(6)" ::: "memory");
        else                        asm volatile("s_waitcnt vmcnt(8)" ::: "memory");
        __builtin_amdgcn_sched_barrier(0);
        __builtin_amdgcn_s_barrier();
        __builtin_amdgcn_sched_barrier(0);
        const int v = (kk == 0) ? u + 1 : u + 2;
        const int kkq = kk ^ 1;
        STAGE_A(v, kkq);
        STAGE_B(v, kkq);
        const __bf16* Ab = lds + buf * (BM * 64) + kk * (BM * 32);
        const __bf16* Bb = lds + BM * 128 + buf * (BN * 64) + kk * (BN * 32);
        bf16x8 bfr[4];
#pragma unroll
        for (int n = 0; n < 4; ++n)
          bfr[n] = *(const bf16x8*)(Bb + (wn * 64 + n * 16) * 32 + fragoff);
#pragma unroll
        for (int mg = 0; mg < MG; ++mg) {
          bf16x8 afr[CL];
#pragma unroll
          for (int i = 0; i < CL; ++i)
            afr[i] = *(const bf16x8*)(Ab + (wr * (BM / WM) + (mg * 4 + i) * 16) * 32 + fragoff);
          __builtin_amdgcn_s_setprio(1);
#pragma unroll
          for (int i = 0; i < CL; ++i)
#pragma unroll
            for (int n = 0; n < 4; ++n)
              acc[mg * 4 + i][n] =
                  __builtin_amdgcn_mfma_f32_16x16x32_bf16(afr[i], bfr[n], acc[mg * 4 + i][n], 0, 0, 0);
          __builtin_amdgcn_s_setprio(0);
        }
      }
    }
  }

  if constexpr (EPI == 5) {
    // fused qkv postprocess. Wave's 64 cols = one head slice.
    const int colw = bcol + wn * 64;
    const int secw = colw >> 10;          // 0=q 1=k 2=v
    const int h = (colw >> 6) & 15;
#pragma unroll
    for (int m = 0; m < MF; ++m) {
      int row0 = brow + wr * (BM / WM) + m * 16 + lg * 4;
      int bb = row0 >> 10;
      int t0 = row0 & 1023;
      int bh = bb * 16 + h;
      if (secw < 2) {
        __bf16* base = (secw == 0 ? Qr : Kr) + ((size_t)bh * T_SEQ + t0) * 64;
#pragma unroll
        for (int n = 0; n < 2; ++n) {
          int din = n * 16 + lr;
#pragma unroll
          for (int rr = 0; rr < 4; ++rr) {
            float a = acc[m][n][rr], b2 = acc[m][n + 2][rr];
            float cs = Tab[(t0 + rr) * 32 + din];
            float sn = Tab[32768 + (t0 + rr) * 32 + din];
            base[(size_t)rr * 64 + din]      = (__bf16)(a * cs - b2 * sn);
            base[(size_t)rr * 64 + din + 32] = (__bf16)(a * sn + b2 * cs);
          }
        }
      } else {
#pragma unroll
        for (int n = 0; n < 4; ++n) {
          int din = n * 16 + lr;
          bf16x4 pk;
#pragma unroll
          for (int rr = 0; rr < 4; ++rr) pk[rr] = (__bf16)acc[m][n][rr];
          *(bf16x4*)&Vt[((size_t)bh * 64 + din) * T_SEQ + t0] = pk;
        }
      }
    }
  } else {
#pragma unroll
    for (int m = 0; m < MF; ++m) {
#pragma unroll
      for (int n = 0; n < 4; ++n) {
#pragma unroll
        for (int rr = 0; rr < 4; ++rr) {
          int row = brow + wr * (BM / WM) + m * 16 + lg * 4 + rr;
          int col = bcol + wn * 64 + n * 16 + lr;
          size_t off = (size_t)row * ldc + col;
          float vv = acc[m][n][rr];
          if (EPI == 0) {
            ((float*)Cout)[off] = vv;
          } else if (EPI == 1) {
            ((float*)Cout)[off] = Cin[off] + vv;
          } else {
            float uv = __shfl_xor(vv, 1);
            if ((lr & 1) == 0) {
              float r = vv / (1.f + __expf(-vv)) * uv;
              ((__bf16*)Cout)[(size_t)row * ldc + (col >> 1)] = (__bf16)r;
            }
          }
        }
      }
    }
  }
}

// ---------------------------------------------------------------------------
// Flash attention, causal-balanced: block (qp, bh) handles q-blocks qp and
// 15-qp (work = 9 kv-tiles each pair). 4 waves x 16 q-rows, KVBLK=128.
// ---------------------------------------------------------------------------
__global__ __launch_bounds__(256) void attn_kernel(const __bf16* __restrict__ Qr,
                                                   const __bf16* __restrict__ Kr,
                                                   const __bf16* __restrict__ Vt,
                                                   __bf16* __restrict__ o) {
  __shared__ __align__(16) __bf16 lds[28672];
  const int tid = threadIdx.x;
  const int lane = tid & 63, w = tid >> 6;
  const int lr = lane & 15, lg = lane >> 4;
  const int bh = blockIdx.y, b = bh >> 4, h = bh & 15;
  const int qp = blockIdx.x;
  const __bf16* Kg = Kr + (size_t)bh * T_SEQ * 64;
  const __bf16* Vg = Vt + (size_t)bh * 64 * T_SEQ;
  const float scale = 0.125f;
  __bf16* Pw = lds + 20480 + w * 2048;

  for (int qs = 0; qs < 2; ++qs) {
    const int qb = qs ? (15 - qp) : qp;
    const int q0 = qb * 64;
    const __bf16* Qg = Qr + ((size_t)bh * T_SEQ + q0) * 64;

    __syncthreads();   // protect Q region from prior iteration's readers
    {
      int row = ((tid >> 6) << 4) | (tid & 15);
      int j = (tid >> 4) & 3;
      gload16(Qg + row * 64 + j * 8, lds + tid * 8);
      gload16(Qg + row * 64 + 32 + j * 8, lds + 2048 + tid * 8);
    }

    f32x4 accO[4];
#pragma unroll
    for (int n = 0; n < 4; ++n) accO[n] = (f32x4){0.f, 0.f, 0.f, 0.f};
    float mrow[4], lrow[4];
#pragma unroll
    for (int r = 0; r < 4; ++r) { mrow[r] = -1e30f; lrow[r] = 0.f; }

    const int ntile = ((q0 + 63) >> 7) + 1;

    for (int tt = 0; tt < ntile; ++tt) {
      const int j0 = tt * 128;
      __syncthreads();
#pragma unroll
      for (int i = 0; i < 2; ++i) {
        int p = tid + i * 256;
        int row = ((p >> 6) << 4) | (p & 15), j = (p >> 4) & 3;
        const __bf16* src = Kg + (size_t)(j0 + row) * 64 + j * 8;
        gload16(src, lds + 4096 + p * 8);
        gload16(src + 32, lds + 8192 + p * 8);
      }
#pragma unroll
      for (int s = 0; s < 4; ++s) {
        int d = ((tid >> 6) << 4) | (tid & 15), j = (tid >> 4) & 3;
        gload16(Vg + (size_t)d * T_SEQ + j0 + s * 32 + j * 8, lds + 12288 + s * 2048 + tid * 8);
      }
      __syncthreads();

      f32x4 s4[8];
#pragma unroll
      for (int n = 0; n < 8; ++n) s4[n] = (f32x4){0.f, 0.f, 0.f, 0.f};
#pragma unroll
      for (int kk = 0; kk < 2; ++kk) {
        bf16x8 aq = *(const bf16x8*)(lds + kk * 2048 + (w * 64 + lg * 16 + lr) * 8);
        __builtin_amdgcn_s_setprio(1);
#pragma unroll
        for (int jf = 0; jf < 8; ++jf) {
          bf16x8 bk = *(const bf16x8*)(lds + 4096 + kk * 4096 + (jf * 64 + lg * 16 + lr) * 8);
          s4[jf] = __builtin_amdgcn_mfma_f32_16x16x32_bf16(aq, bk, s4[jf], 0, 0, 0);
        }
        __builtin_amdgcn_s_setprio(0);
      }

      float pm[4];
#pragma unroll
      for (int r = 0; r < 4; ++r) pm[r] = -1e30f;
#pragma unroll
      for (int jf = 0; jf < 8; ++jf) {
        int gj = j0 + jf * 16 + lr;
#pragma unroll
        for (int r = 0; r < 4; ++r) {
          int gq = q0 + w * 16 + lg * 4 + r;
          float sv = s4[jf][r] * scale;
          if (gj > gq) sv = -1e30f;
          s4[jf][r] = sv;
          pm[r] = fmaxf(pm[r], sv);
        }
      }
#pragma unroll
      for (int r = 0; r < 4; ++r) {
#pragma unroll
        for (int m = 8; m >= 1; m >>= 1) pm[r] = fmaxf(pm[r], __shfl_xor(pm[r], m, 64));
      }
      float alpha[4];
#pragma unroll
      for (int r = 0; r < 4; ++r) {
        float mn = fmaxf(mrow[r], pm[r]);
        alpha[r] = expf(mrow[r] - mn);
        mrow[r] = mn;
      }
      float ps[4] = {0.f, 0.f, 0.f, 0.f};
#pragma unroll
      for (int jf = 0; jf < 8; ++jf) {
#pragma unroll
        for (int r = 0; r < 4; ++r) {
          float p = expf(s4[jf][r] - mrow[r]);
          s4[jf][r] = p;
          ps[r] += p;
        }
      }
#pragma unroll
      for (int r = 0; r < 4; ++r) {
#pragma unroll
        for (int m = 8; m >= 1; m >>= 1) ps[r] += __shfl_xor(ps[r], m, 64);
        lrow[r] = lrow[r] * alpha[r] + ps[r];
      }
#pragma unroll
      for (int n = 0; n < 4; ++n) {
#pragma unroll
        for (int r = 0; r < 4; ++r) accO[n][r] *= alpha[r];
      }

#pragma unroll
      for (int jf = 0; jf < 8; ++jf) {
        int s = jf >> 1;
        int rem = ((jf & 1) << 4) + lr;
        int base = s * 512 + (rem >> 3) * 128 + (rem & 7);
#pragma unroll
        for (int r = 0; r < 4; ++r) {
          int qloc = lg * 4 + r;
          Pw[base + qloc * 8] = (__bf16)s4[jf][r];
        }
      }
      asm volatile("s_waitcnt lgkmcnt(0)" ::: "memory");
      __builtin_amdgcn_sched_barrier(0);

#pragma unroll
      for (int s = 0; s < 4; ++s) {
        bf16x8 pa = *(const bf16x8*)(Pw + s * 512 + (lg * 16 + lr) * 8);
        __builtin_amdgcn_s_setprio(1);
#pragma unroll
        for (int nd = 0; nd < 4; ++nd) {
          bf16x8 bv = *(const bf16x8*)(lds + 12288 + s * 2048 + (nd * 64 + lg * 16 + lr) * 8);
          accO[nd] = __builtin_amdgcn_mfma_f32_16x16x32_bf16(pa, bv, accO[nd], 0, 0, 0);
        }
        __builtin_amdgcn_s_setprio(0);
      }
    }

#pragma unroll
    for (int nd = 0; nd < 4; ++nd) {
#pragma unroll
      for (int r = 0; r < 4; ++r) {
        int gq = q0 + w * 16 + lg * 4 + r;
        float val = accO[nd][r] / lrow[r];
        o[(size_t)(b * T_SEQ + gq) * D_MODEL + h * 64 + nd * 16 + lr] = (__bf16)val;
      }
    }
  }
}

// ---------------------------------------------------------------------------
extern "C" void kernel_launch(void* const* d_in, const int* in_sizes, int n_in,
                              void* d_out, int out_size, void* d_ws, size_t ws_size,
                              hipStream_t stream) {
  const int*   idx     = (const int*)d_in[0];
  const float* W_emb   = (const float*)d_in[1];
  const float* norm1_w = (const float*)d_in[2];
  const float* Wqkv    = (const float*)d_in[3];
  const float* Wout    = (const float*)d_in[4];
  const float* norm2_w = (const float*)d_in[5];
  const float* Wg      = (const float*)d_in[6];
  const float* Wu      = (const float*)d_in[7];
  const float* Wd      = (const float*)d_in[8];
  const float* fnorm   = (const float*)d_in[9];
  float* out = (float*)d_out;

  float*  x    = (float*)d_ws;                              // 2048*1024 f32
  float*  tab  = x + (size_t)NTOK * D_MODEL;                // 2*32768 f32
  __bf16* hb   = (__bf16*)(tab + 2 * 32768);                // 2048*1024
  __bf16* ob   = hb + (size_t)NTOK * D_MODEL;               // 2048*1024
  __bf16* ga   = ob + (size_t)NTOK * D_MODEL;               // 2048*2816
  __bf16* Qrb  = ga + (size_t)NTOK * HID_PAD;               // 32*1024*64
  __bf16* Krb  = Qrb + (size_t)32 * T_SEQ * 64;
  __bf16* Vtb  = Krb + (size_t)32 * T_SEQ * 64;
  __bf16* wbuf = Vtb + (size_t)32 * T_SEQ * 64;

  __bf16* wqkvT = wbuf;                                     // [3072][1024]
  __bf16* woutT = wqkvT + (size_t)3 * D_MODEL * D_MODEL;    // [1024][1024]
  __bf16* wguT  = woutT + (size_t)D_MODEL * D_MODEL;        // [5632][1024]
  __bf16* wdT   = wguT + (size_t)2 * HID_PAD * D_MODEL;     // [1024][2816]

  embed_kernel<<<NTOK, 256, 0, stream>>>(idx, W_emb, x);
  rope_table_kernel<<<128, 256, 0, stream>>>(tab);

  for (int l = 0; l < NLAYER; ++l) {
    tp5_kernel<<<3136, 256, 0, stream>>>(
        Wqkv + (size_t)l * D_MODEL * 3 * D_MODEL,
        Wout + (size_t)l * D_MODEL * D_MODEL,
        Wg + (size_t)l * D_MODEL * HID,
        Wu + (size_t)l * D_MODEL * HID,
        Wd + (size_t)l * HID * D_MODEL,
        wqkvT, woutT, wguT, wdT);

    rmsnorm_kernel<<<NTOK, 256, 0, stream>>>(x, norm1_w + (size_t)l * D_MODEL, hb);
    gemm8<128, 256, 2, 4, 5><<<dim3(16, 12), 512, 0, stream>>>(
        hb, wqkvT, nullptr, nullptr, D_MODEL, 3 * D_MODEL, tab, Qrb, Krb, Vtb);
    attn_kernel<<<dim3(8, 32), 256, 0, stream>>>(Qrb, Krb, Vtb, ob);
    gemm8<128, 64, 4, 1, 1><<<dim3(16, 16), 256, 0, stream>>>(
        ob, woutT, x, x, D_MODEL, D_MODEL, nullptr, nullptr, nullptr, nullptr);
    rmsnorm_kernel<<<NTOK, 256, 0, stream>>>(x, norm2_w + (size_t)l * D_MODEL, hb);
    gemm8<256, 256, 2, 4, 4><<<dim3(8, 22), 512, 0, stream>>>(
        hb, wguT, nullptr, ga, D_MODEL, HID_PAD, nullptr, nullptr, nullptr, nullptr);
    gemm8<128, 64, 4, 1, 1><<<dim3(16, 16), 256, 0, stream>>>(
        ga, wdT, x, x, HID_PAD, D_MODEL, nullptr, nullptr, nullptr, nullptr);
  }

  rmsnorm_kernel<<<NTOK, 256, 0, stream>>>(x, fnorm, hb);
  convert_bf16_kernel<<<2048, 256, 0, stream>>>(W_emb, wbuf, VOCAB * D_MODEL / 4);
  gemm8<256, 256, 2, 4, 0><<<dim3(8, 125), 512, 0, stream>>>(
      hb, wbuf, nullptr, out, D_MODEL, VOCAB, nullptr, nullptr, nullptr, nullptr);
}